// Round 1
// baseline (1346.525 us; speedup 1.0000x reference)
//
#include <hip/hip_runtime.h>
#include <math.h>

#define N_TOK 8192
#define DMODEL 512
#define NEXP 8
#define HEXP 1024
#define RHDIM 256
#define KP 4672          // IN_DIM=4611 padded to multiple of 64 (zero-filled)
#define IN_REAL 4611
#define LDSW 56          // LDS row stride in bf16 elems (112 B): 16B-aligned, 2-way-conflict pattern
#define NPAIR (N_TOK * 2)

typedef unsigned short u16;
typedef __bf16 bf16x8 __attribute__((ext_vector_type(8)));
typedef float f32x4 __attribute__((ext_vector_type(4)));

__device__ inline u16 f2bf(float f) {
    union { float f; unsigned u; } x; x.f = f;
    unsigned r = x.u + 0x7FFFu + ((x.u >> 16) & 1u);   // round-to-nearest-even
    return (u16)(r >> 16);
}
__device__ inline float bf2f(u16 u) {
    union { unsigned u; float f; } x; x.u = ((unsigned)u) << 16;
    return x.f;
}
__device__ inline float gelu_exact(float v) {
    return 0.5f * v * (1.f + erff(v * 0.70710678118654752440f));
}

// ---- block stats for 512-thread blocks: returns (mean, rsqrt(var+eps)) ----
__device__ inline float2 bstats512(float v, int tid, float* red) {
    float s = v, q = v * v;
    #pragma unroll
    for (int o = 32; o > 0; o >>= 1) {
        s += __shfl_xor(s, o);
        q += __shfl_xor(q, o);
    }
    __syncthreads();                       // protect red[] from previous call's readers
    if ((tid & 63) == 0) { red[(tid >> 6) * 2] = s; red[(tid >> 6) * 2 + 1] = q; }
    __syncthreads();
    if (tid == 0) {
        float S = 0.f, Q = 0.f;
        #pragma unroll
        for (int i = 0; i < 8; i++) { S += red[i * 2]; Q += red[i * 2 + 1]; }
        float m = S * (1.f / 512.f);
        float var = fmaxf(Q * (1.f / 512.f) - m * m, 0.f);
        red[16] = m;
        red[17] = rsqrtf(var + 1e-5f);
    }
    __syncthreads();
    return make_float2(red[16], red[17]);
}

// ---- transpose fp32 [K0,H] -> bf16 [H,KPd] (zero-fill k>=K0), optional hi/lo split ----
__global__ __launch_bounds__(256)
void transpose_f32_bf16(const float* __restrict__ src, u16* __restrict__ dhi, u16* __restrict__ dlo,
                        int K0, int KPd, int H, size_t sbatch, size_t dbatch) {
    __shared__ float tile[32][33];
    int bz = blockIdx.z;
    src += (size_t)bz * sbatch;
    size_t dob = (size_t)bz * dbatch;
    int k0 = blockIdx.x * 32, h0 = blockIdx.y * 32;
    int tx = threadIdx.x, ty = threadIdx.y;
    for (int i = ty; i < 32; i += 8) {
        int k = k0 + i;
        tile[i][tx] = (k < K0) ? src[(size_t)k * H + (h0 + tx)] : 0.f;
    }
    __syncthreads();
    for (int i = ty; i < 32; i += 8) {
        int h = h0 + i, k = k0 + tx;
        float v = tile[tx][i];
        u16 hv = f2bf(v);
        dhi[dob + (size_t)h * KPd + k] = hv;
        if (dlo) dlo[dob + (size_t)h * KPd + k] = f2bf(v - bf2f(hv));
    }
}

// ---- build fusion input x (9 LayerNorms + mask), emit bf16 hi/lo split ----
__global__ __launch_bounds__(512)
void build_x(const float* __restrict__ z1, const float* __restrict__ z2, const float* __restrict__ z3,
             const float* __restrict__ mask,
             const float* __restrict__ ln_g, const float* __restrict__ ln_b,
             const float* __restrict__ lnp_g, const float* __restrict__ lnp_b,
             u16* __restrict__ xhi, u16* __restrict__ xlo) {
    __shared__ float red[18];
    int n = blockIdx.x, d = threadIdx.x;
    float a = z1[(size_t)n * DMODEL + d];
    float b = z2[(size_t)n * DMODEL + d];
    float c = z3[(size_t)n * DMODEL + d];
    float gg = ln_g[d], bb = ln_b[d], pg = lnp_g[d], pb = lnp_b[d];
    size_t base = (size_t)n * KP;

    auto emit = [&](int seg, float v) {
        u16 h = f2bf(v);
        xhi[base + seg * DMODEL + d] = h;
        xlo[base + seg * DMODEL + d] = f2bf(v - bf2f(h));
    };
    float2 s;
    s = bstats512(a, d, red); float z1n = (a - s.x) * s.y * gg + bb;
    s = bstats512(b, d, red); float z2n = (b - s.x) * s.y * gg + bb;
    s = bstats512(c, d, red); float z3n = (c - s.x) * s.y * gg + bb;
    emit(0, z1n); emit(1, z2n); emit(2, z3n);
    auto pln = [&](int seg, float v) {
        float2 st = bstats512(v, d, red);
        emit(seg, (v - st.x) * st.y * pg + pb);
    };
    pln(3, z1n - z2n); pln(4, z1n - z3n); pln(5, z2n - z3n);
    pln(6, z1n * z2n); pln(7, z1n * z3n); pln(8, z2n * z3n);
    if (d < 64) {   // mask cols 4608..4610 + zero pad 4611..4671
        int col = 9 * DMODEL + d;
        float v = (d < 3) ? mask[(size_t)n * 3 + d] : 0.f;
        u16 h = f2bf(v);
        xhi[base + col] = h;
        xlo[base + col] = f2bf(v - bf2f(h));
    }
}

// ================= 128x128 bf16 MFMA GEMM bodies =================
// A-frag: A[m=lane&15][k=(lane>>4)*8+j]; B-frag: B[n=lane&15][k=(lane>>4)*8+j] (B^T in LDS)
// C/D: row=(lane>>4)*4+reg, col=lane&15  [m89-verified]

// ---- router fc1: partial GEMM, part = region(3: hh,hl,lh) x k-half(2) ----
__global__ __launch_bounds__(256)
void router_fc1(const u16* __restrict__ xhi, const u16* __restrict__ xlo,
                const u16* __restrict__ rw1hi, const u16* __restrict__ rw1lo,
                float* __restrict__ rpart) {
    int mt = blockIdx.x, nt = blockIdx.y, part = blockIdx.z;
    int region = part >> 1, half = part & 1;
    const u16* A = (region == 2) ? xlo : xhi;        // hh: hi*hi, hl: hi*lo, lh: lo*hi
    const u16* B = (region == 1) ? rw1lo : rw1hi;
    int kbase = half * (KP / 2);

    __shared__ u16 lA[128 * LDSW];
    __shared__ u16 lB[128 * LDSW];
    int t = threadIdx.x;
    int ar0 = t >> 2, ac0 = (t & 3) * 8, ar1 = ar0 + 64;
    const u16* arow0 = A + (size_t)(mt * 128 + ar0) * KP;
    const u16* arow1 = A + (size_t)(mt * 128 + ar1) * KP;
    const u16* brow0 = B + (size_t)(nt * 128 + ar0) * KP;
    const u16* brow1 = B + (size_t)(nt * 128 + ar1) * KP;

    f32x4 acc[4][4];
    f32x4 z4 = {0.f, 0.f, 0.f, 0.f};
    #pragma unroll
    for (int i = 0; i < 4; i++)
        #pragma unroll
        for (int j = 0; j < 4; j++) acc[i][j] = z4;

    int lane = t & 63, wave = t >> 6;
    int wm = (wave & 1) * 64, wn = (wave >> 1) * 64;
    int fr = lane & 15, fko = (lane >> 4) * 8;

    for (int k0 = kbase; k0 < kbase + KP / 2; k0 += 32) {
        __syncthreads();
        *(int4*)&lA[ar0 * LDSW + ac0] = *(const int4*)&arow0[k0 + ac0];
        *(int4*)&lA[ar1 * LDSW + ac0] = *(const int4*)&arow1[k0 + ac0];
        *(int4*)&lB[ar0 * LDSW + ac0] = *(const int4*)&brow0[k0 + ac0];
        *(int4*)&lB[ar1 * LDSW + ac0] = *(const int4*)&brow1[k0 + ac0];
        __syncthreads();
        bf16x8 af[4], bf[4];
        #pragma unroll
        for (int i = 0; i < 4; i++) af[i] = *(const bf16x8*)&lA[(wm + i * 16 + fr) * LDSW + fko];
        #pragma unroll
        for (int j = 0; j < 4; j++) bf[j] = *(const bf16x8*)&lB[(wn + j * 16 + fr) * LDSW + fko];
        #pragma unroll
        for (int i = 0; i < 4; i++)
            #pragma unroll
            for (int j = 0; j < 4; j++)
                acc[i][j] = __builtin_amdgcn_mfma_f32_16x16x32_bf16(af[i], bf[j], acc[i][j], 0, 0, 0);
    }
    float* outp = rpart + (size_t)part * ((size_t)N_TOK * RHDIM);
    int q = lane >> 4, cn = lane & 15;
    #pragma unroll
    for (int i = 0; i < 4; i++)
        #pragma unroll
        for (int rr = 0; rr < 4; rr++) {
            int mg = mt * 128 + wm + i * 16 + q * 4 + rr;
            #pragma unroll
            for (int j = 0; j < 4; j++)
                outp[(size_t)mg * RHDIM + nt * 128 + wn + j * 16 + cn] = acc[i][j][rr];
        }
}

__global__ void router_act(const float* __restrict__ rpart, const float* __restrict__ r_b1,
                           float* __restrict__ rh) {
    int idx = blockIdx.x * 256 + threadIdx.x;
    float v = 0.f;
    #pragma unroll
    for (int p = 0; p < 6; p++) v += rpart[(size_t)p * ((size_t)N_TOK * RHDIM) + idx];
    v += r_b1[idx & (RHDIM - 1)];
    rh[idx] = gelu_exact(v);
}

// ---- logits + top-2 + gates + expert scatter: one wave per token ----
__global__ __launch_bounds__(256)
void logits_topk(const float* __restrict__ rh, const float* __restrict__ r_w2,
                 const float* __restrict__ r_b2, const float* __restrict__ log_temp,
                 float* __restrict__ pgate, int* __restrict__ pexp,
                 int* __restrict__ lists, int* __restrict__ counts) {
    int t = threadIdx.x, wave = t >> 6, lane = t & 63;
    int n = blockIdx.x * 4 + wave;
    int e = lane & 7, ch = lane >> 3;
    const float* r = rh + (size_t)n * RHDIM;
    float s = 0.f;
    #pragma unroll
    for (int k = 0; k < 32; k++) s += r[ch * 32 + k] * r_w2[(ch * 32 + k) * 8 + e];
    s += __shfl_xor(s, 8);
    s += __shfl_xor(s, 16);
    s += __shfl_xor(s, 32);
    float temp = fminf(fmaxf(expf(log_temp[0]), 1e-3f), 100.f);
    float logit = (s + r_b2[e]) / temp;
    float l[8];
    #pragma unroll
    for (int i = 0; i < 8; i++) l[i] = __shfl(logit, i);
    if (lane == 0) {
        int i1 = 0;
        #pragma unroll
        for (int i = 1; i < 8; i++) if (l[i] > l[i1]) i1 = i;   // first-occurrence max (matches top_k)
        int i2 = (i1 == 0) ? 1 : 0;
        #pragma unroll
        for (int i = 0; i < 8; i++) if (i != i1 && l[i] > l[i2]) i2 = i;
        float p = expf(l[i2] - l[i1]);
        float g1 = 1.f / (1.f + p);
        float g2 = p / (1.f + p);
        pgate[n * 2] = g1;     pexp[n * 2] = i1;
        pgate[n * 2 + 1] = g2; pexp[n * 2 + 1] = i2;
        int pos1 = atomicAdd(&counts[i1], 1);
        lists[(size_t)i1 * N_TOK + pos1] = n * 2;
        int pos2 = atomicAdd(&counts[i2], 1);
        lists[(size_t)i2 * N_TOK + pos2] = n * 2 + 1;
    }
}

// ---- expert fc1: gathered [cnt,KP] x [KP,H] bf16 GEMM, gelu epilogue -> eh bf16 ----
__global__ __launch_bounds__(256)
void expert_fc1(const u16* __restrict__ xhi, const u16* __restrict__ w1t,
                const float* __restrict__ e_b1, const int* __restrict__ lists,
                const int* __restrict__ counts, u16* __restrict__ eh) {
    int e = blockIdx.z, mt = blockIdx.x, nt = blockIdx.y;
    int cnt = counts[e];
    if (mt * 128 >= cnt) return;

    __shared__ u16 lA[128 * LDSW];
    __shared__ u16 lB[128 * LDSW];
    __shared__ int rows[128];
    int t = threadIdx.x;
    if (t < 128) {
        int m = mt * 128 + t;
        rows[t] = lists[(size_t)e * N_TOK + (m < cnt ? m : 0)];   // clamp tail to a valid entry
    }
    __syncthreads();

    int ar0 = t >> 2, ac0 = (t & 3) * 8, ar1 = ar0 + 64;
    const u16* arow0 = xhi + (size_t)(rows[ar0] >> 1) * KP;
    const u16* arow1 = xhi + (size_t)(rows[ar1] >> 1) * KP;
    const u16* wbase = w1t + (size_t)e * HEXP * KP + (size_t)(nt * 128) * KP;
    const u16* brow0 = wbase + (size_t)ar0 * KP;
    const u16* brow1 = wbase + (size_t)ar1 * KP;

    f32x4 acc[4][4];
    f32x4 z4 = {0.f, 0.f, 0.f, 0.f};
    #pragma unroll
    for (int i = 0; i < 4; i++)
        #pragma unroll
        for (int j = 0; j < 4; j++) acc[i][j] = z4;

    int lane = t & 63, wave = t >> 6;
    int wm = (wave & 1) * 64, wn = (wave >> 1) * 64;
    int fr = lane & 15, fko = (lane >> 4) * 8;

    for (int k0 = 0; k0 < KP; k0 += 32) {
        __syncthreads();
        *(int4*)&lA[ar0 * LDSW + ac0] = *(const int4*)&arow0[k0 + ac0];
        *(int4*)&lA[ar1 * LDSW + ac0] = *(const int4*)&arow1[k0 + ac0];
        *(int4*)&lB[ar0 * LDSW + ac0] = *(const int4*)&brow0[k0 + ac0];
        *(int4*)&lB[ar1 * LDSW + ac0] = *(const int4*)&brow1[k0 + ac0];
        __syncthreads();
        bf16x8 af[4], bf[4];
        #pragma unroll
        for (int i = 0; i < 4; i++) af[i] = *(const bf16x8*)&lA[(wm + i * 16 + fr) * LDSW + fko];
        #pragma unroll
        for (int j = 0; j < 4; j++) bf[j] = *(const bf16x8*)&lB[(wn + j * 16 + fr) * LDSW + fko];
        #pragma unroll
        for (int i = 0; i < 4; i++)
            #pragma unroll
            for (int j = 0; j < 4; j++)
                acc[i][j] = __builtin_amdgcn_mfma_f32_16x16x32_bf16(af[i], bf[j], acc[i][j], 0, 0, 0);
    }
    int q = lane >> 4, cn = lane & 15;
    #pragma unroll
    for (int i = 0; i < 4; i++)
        #pragma unroll
        for (int rr = 0; rr < 4; rr++) {
            int ml = wm + i * 16 + q * 4 + rr;
            int mg = mt * 128 + ml;
            if (mg < cnt) {
                int entry = rows[ml];
                #pragma unroll
                for (int j = 0; j < 4; j++) {
                    int col = nt * 128 + wn + j * 16 + cn;
                    float v = acc[i][j][rr] + e_b1[(size_t)e * HEXP + col];
                    eh[(size_t)entry * HEXP + col] = f2bf(gelu_exact(v));
                }
            }
        }
}

// ---- expert fc2: gathered [cnt,H] x [H,D] bf16 GEMM -> per-slot fp32 outs ----
__global__ __launch_bounds__(256)
void expert_fc2(const u16* __restrict__ eh, const u16* __restrict__ w2t,
                const int* __restrict__ lists, const int* __restrict__ counts,
                float* __restrict__ outs) {
    int e = blockIdx.z, mt = blockIdx.x, nt = blockIdx.y;
    int cnt = counts[e];
    if (mt * 128 >= cnt) return;

    __shared__ u16 lA[128 * LDSW];
    __shared__ u16 lB[128 * LDSW];
    __shared__ int rows[128];
    int t = threadIdx.x;
    if (t < 128) {
        int m = mt * 128 + t;
        rows[t] = lists[(size_t)e * N_TOK + (m < cnt ? m : 0)];
    }
    __syncthreads();

    int ar0 = t >> 2, ac0 = (t & 3) * 8, ar1 = ar0 + 64;
    const u16* arow0 = eh + (size_t)rows[ar0] * HEXP;
    const u16* arow1 = eh + (size_t)rows[ar1] * HEXP;
    const u16* wbase = w2t + (size_t)e * DMODEL * HEXP + (size_t)(nt * 128) * HEXP;
    const u16* brow0 = wbase + (size_t)ar0 * HEXP;
    const u16* brow1 = wbase + (size_t)ar1 * HEXP;

    f32x4 acc[4][4];
    f32x4 z4 = {0.f, 0.f, 0.f, 0.f};
    #pragma unroll
    for (int i = 0; i < 4; i++)
        #pragma unroll
        for (int j = 0; j < 4; j++) acc[i][j] = z4;

    int lane = t & 63, wave = t >> 6;
    int wm = (wave & 1) * 64, wn = (wave >> 1) * 64;
    int fr = lane & 15, fko = (lane >> 4) * 8;

    for (int k0 = 0; k0 < HEXP; k0 += 32) {
        __syncthreads();
        *(int4*)&lA[ar0 * LDSW + ac0] = *(const int4*)&arow0[k0 + ac0];
        *(int4*)&lA[ar1 * LDSW + ac0] = *(const int4*)&arow1[k0 + ac0];
        *(int4*)&lB[ar0 * LDSW + ac0] = *(const int4*)&brow0[k0 + ac0];
        *(int4*)&lB[ar1 * LDSW + ac0] = *(const int4*)&brow1[k0 + ac0];
        __syncthreads();
        bf16x8 af[4], bf[4];
        #pragma unroll
        for (int i = 0; i < 4; i++) af[i] = *(const bf16x8*)&lA[(wm + i * 16 + fr) * LDSW + fko];
        #pragma unroll
        for (int j = 0; j < 4; j++) bf[j] = *(const bf16x8*)&lB[(wn + j * 16 + fr) * LDSW + fko];
        #pragma unroll
        for (int i = 0; i < 4; i++)
            #pragma unroll
            for (int j = 0; j < 4; j++)
                acc[i][j] = __builtin_amdgcn_mfma_f32_16x16x32_bf16(af[i], bf[j], acc[i][j], 0, 0, 0);
    }
    int q = lane >> 4, cn = lane & 15;
    #pragma unroll
    for (int i = 0; i < 4; i++)
        #pragma unroll
        for (int rr = 0; rr < 4; rr++) {
            int ml = wm + i * 16 + q * 4 + rr;
            int mg = mt * 128 + ml;
            if (mg < cnt) {
                int entry = rows[ml];
                #pragma unroll
                for (int j = 0; j < 4; j++) {
                    int col = nt * 128 + wn + j * 16 + cn;
                    outs[(size_t)entry * DMODEL + col] = acc[i][j][rr];
                }
            }
        }
}

// ---- combine: gate*(outs+b2) + masked residual + final LN ----
__global__ __launch_bounds__(512)
void combine_ln(const float* __restrict__ outs, const float* __restrict__ pgate,
                const int* __restrict__ pexp, const float* __restrict__ e_b2,
                const float* __restrict__ mask, const u16* __restrict__ xhi,
                const u16* __restrict__ xlo, const float* __restrict__ oln_g,
                const float* __restrict__ oln_b, float* __restrict__ out) {
    __shared__ float red[18];
    int n = blockIdx.x, d = threadIdx.x;
    float g0 = pgate[n * 2], g1 = pgate[n * 2 + 1];
    int e0 = pexp[n * 2], e1 = pexp[n * 2 + 1];
    float o = g0 * (outs[(size_t)(n * 2) * DMODEL + d] + e_b2[(size_t)e0 * DMODEL + d])
            + g1 * (outs[(size_t)(n * 2 + 1) * DMODEL + d] + e_b2[(size_t)e1 * DMODEL + d]);
    float m0 = mask[n * 3 + 0], m1 = mask[n * 3 + 1], m2 = mask[n * 3 + 2];
    float denom = fmaxf(m0 + m1 + m2, 1.f);
    size_t xb = (size_t)n * KP;
    float z1n = bf2f(xhi[xb + d]) + bf2f(xlo[xb + d]);                       // hi+lo = fp32-exact
    float z2n = bf2f(xhi[xb + DMODEL + d]) + bf2f(xlo[xb + DMODEL + d]);
    float z3n = bf2f(xhi[xb + 2 * DMODEL + d]) + bf2f(xlo[xb + 2 * DMODEL + d]);
    float z = o + (m0 * z1n + m1 * z2n + m2 * z3n) / denom;
    float2 st = bstats512(z, d, red);
    out[(size_t)n * DMODEL + d] = (z - st.x) * st.y * oln_g[d] + oln_b[d];
}

extern "C" void kernel_launch(void* const* d_in, const int* in_sizes, int n_in,
                              void* d_out, int out_size, void* d_ws, size_t ws_size,
                              hipStream_t stream) {
    (void)in_sizes; (void)n_in; (void)out_size; (void)ws_size;
    const float* z1       = (const float*)d_in[0];
    const float* z2       = (const float*)d_in[1];
    const float* z3       = (const float*)d_in[2];
    const float* mask     = (const float*)d_in[3];
    const float* ln_g     = (const float*)d_in[4];
    const float* ln_b     = (const float*)d_in[5];
    const float* lnp_g    = (const float*)d_in[6];
    const float* lnp_b    = (const float*)d_in[7];
    const float* oln_g    = (const float*)d_in[8];
    const float* oln_b    = (const float*)d_in[9];
    const float* r_w1     = (const float*)d_in[10];
    const float* r_b1     = (const float*)d_in[11];
    const float* r_w2     = (const float*)d_in[12];
    const float* r_b2     = (const float*)d_in[13];
    const float* log_temp = (const float*)d_in[14];
    const float* e_w1     = (const float*)d_in[15];
    const float* e_b1     = (const float*)d_in[16];
    const float* e_w2     = (const float*)d_in[17];
    const float* e_b2     = (const float*)d_in[18];
    float* out = (float*)d_out;

    char* p = (char*)d_ws;
    auto carve = [&](size_t bytes) { char* r = p; p += (bytes + 255) & ~(size_t)255; return r; };
    u16*   xhi    = (u16*)carve((size_t)N_TOK * KP * 2);
    u16*   xlo    = (u16*)carve((size_t)N_TOK * KP * 2);
    u16*   w1t    = (u16*)carve((size_t)NEXP * HEXP * KP * 2);
    u16*   w2t    = (u16*)carve((size_t)NEXP * DMODEL * HEXP * 2);
    u16*   rw1hi  = (u16*)carve((size_t)RHDIM * KP * 2);
    u16*   rw1lo  = (u16*)carve((size_t)RHDIM * KP * 2);
    float* rpart  = (float*)carve((size_t)6 * N_TOK * RHDIM * 4);
    float* rh     = (float*)carve((size_t)N_TOK * RHDIM * 4);
    u16*   eh     = (u16*)carve((size_t)NPAIR * HEXP * 2);
    float* outsb  = (float*)carve((size_t)NPAIR * DMODEL * 4);
    float* pgate  = (float*)carve((size_t)NPAIR * 4);
    int*   pexp   = (int*)carve((size_t)NPAIR * 4);
    int*   lists  = (int*)carve((size_t)NEXP * N_TOK * 4);
    int*   counts = (int*)carve(256);

    dim3 tb(32, 8);
    transpose_f32_bf16<<<dim3(KP / 32, HEXP / 32, NEXP), tb, 0, stream>>>(
        e_w1, w1t, (u16*)nullptr, IN_REAL, KP, HEXP, (size_t)IN_REAL * HEXP, (size_t)HEXP * KP);
    transpose_f32_bf16<<<dim3(HEXP / 32, DMODEL / 32, NEXP), tb, 0, stream>>>(
        e_w2, w2t, (u16*)nullptr, HEXP, HEXP, DMODEL, (size_t)HEXP * DMODEL, (size_t)DMODEL * HEXP);
    transpose_f32_bf16<<<dim3(KP / 32, RHDIM / 32, 1), tb, 0, stream>>>(
        r_w1, rw1hi, rw1lo, IN_REAL, KP, RHDIM, (size_t)0, (size_t)0);

    build_x<<<N_TOK, 512, 0, stream>>>(z1, z2, z3, mask, ln_g, ln_b, lnp_g, lnp_b, xhi, xlo);

    router_fc1<<<dim3(64, 2, 6), 256, 0, stream>>>(xhi, xlo, rw1hi, rw1lo, rpart);
    router_act<<<(N_TOK * RHDIM) / 256, 256, 0, stream>>>(rpart, r_b1, rh);

    hipMemsetAsync(counts, 0, 256, stream);
    logits_topk<<<N_TOK / 4, 256, 0, stream>>>(rh, r_w2, r_b2, log_temp, pgate, pexp, lists, counts);

    expert_fc1<<<dim3(64, HEXP / 128, NEXP), 256, 0, stream>>>(xhi, w1t, e_b1, lists, counts, eh);
    expert_fc2<<<dim3(64, DMODEL / 128, NEXP), 256, 0, stream>>>(eh, w2t, lists, counts, outsb);

    combine_ln<<<N_TOK, 512, 0, stream>>>(outsb, pgate, pexp, e_b2, mask, xhi, xlo, oln_g, oln_b, out);
}

// Round 2
// 1269.417 us; speedup vs baseline: 1.0607x; 1.0607x over previous
//
#include <hip/hip_runtime.h>
#include <math.h>

#define N_TOK 8192
#define DMODEL 512
#define NEXP 8
#define HEXP 1024
#define RHDIM 256
#define KP 4672          // IN_DIM=4611 padded to multiple of 64 (zero-filled)
#define IN_REAL 4611
#define BK 32            // K-tile; LDS rows are unpadded 32 elems (64 B) for global_load_lds
#define NPAIR (N_TOK * 2)

typedef unsigned short u16;
typedef __bf16 bf16x8 __attribute__((ext_vector_type(8)));
typedef float f32x4 __attribute__((ext_vector_type(4)));

__device__ inline u16 f2bf(float f) {
    union { float f; unsigned u; } x; x.f = f;
    unsigned r = x.u + 0x7FFFu + ((x.u >> 16) & 1u);   // round-to-nearest-even
    return (u16)(r >> 16);
}
__device__ inline float bf2f(u16 u) {
    union { unsigned u; float f; } x; x.u = ((unsigned)u) << 16;
    return x.f;
}
__device__ inline float gelu_exact(float v) {
    return 0.5f * v * (1.f + erff(v * 0.70710678118654752440f));
}

// async global->LDS, 16B per lane; lds base must be wave-uniform, data lands at base + lane*16
__device__ inline void async_cp16(const u16* g, u16* l) {
    __builtin_amdgcn_global_load_lds(
        (const __attribute__((address_space(1))) unsigned int*)g,
        (__attribute__((address_space(3))) unsigned int*)l, 16, 0, 0);
}

// ---- block stats for 512-thread blocks: returns (mean, rsqrt(var+eps)) ----
__device__ inline float2 bstats512(float v, int tid, float* red) {
    float s = v, q = v * v;
    #pragma unroll
    for (int o = 32; o > 0; o >>= 1) {
        s += __shfl_xor(s, o);
        q += __shfl_xor(q, o);
    }
    __syncthreads();
    if ((tid & 63) == 0) { red[(tid >> 6) * 2] = s; red[(tid >> 6) * 2 + 1] = q; }
    __syncthreads();
    if (tid == 0) {
        float S = 0.f, Q = 0.f;
        #pragma unroll
        for (int i = 0; i < 8; i++) { S += red[i * 2]; Q += red[i * 2 + 1]; }
        float m = S * (1.f / 512.f);
        float var = fmaxf(Q * (1.f / 512.f) - m * m, 0.f);
        red[16] = m;
        red[17] = rsqrtf(var + 1e-5f);
    }
    __syncthreads();
    return make_float2(red[16], red[17]);
}

// ---- transpose fp32 [K0,H] -> bf16 [H,KPd] (zero-fill k>=K0), optional hi/lo split ----
__global__ __launch_bounds__(256)
void transpose_f32_bf16(const float* __restrict__ src, u16* __restrict__ dhi, u16* __restrict__ dlo,
                        int K0, int KPd, int H, size_t sbatch, size_t dbatch) {
    __shared__ float tile[32][33];
    int bz = blockIdx.z;
    src += (size_t)bz * sbatch;
    size_t dob = (size_t)bz * dbatch;
    int k0 = blockIdx.x * 32, h0 = blockIdx.y * 32;
    int tx = threadIdx.x, ty = threadIdx.y;
    for (int i = ty; i < 32; i += 8) {
        int k = k0 + i;
        tile[i][tx] = (k < K0) ? src[(size_t)k * H + (h0 + tx)] : 0.f;
    }
    __syncthreads();
    for (int i = ty; i < 32; i += 8) {
        int h = h0 + i, k = k0 + tx;
        float v = tile[tx][i];
        u16 hv = f2bf(v);
        dhi[dob + (size_t)h * KPd + k] = hv;
        if (dlo) dlo[dob + (size_t)h * KPd + k] = f2bf(v - bf2f(hv));
    }
}

// ---- build fusion input x (9 LayerNorms + mask), emit bf16 hi/lo split ----
__global__ __launch_bounds__(512)
void build_x(const float* __restrict__ z1, const float* __restrict__ z2, const float* __restrict__ z3,
             const float* __restrict__ mask,
             const float* __restrict__ ln_g, const float* __restrict__ ln_b,
             const float* __restrict__ lnp_g, const float* __restrict__ lnp_b,
             u16* __restrict__ xhi, u16* __restrict__ xlo) {
    __shared__ float red[18];
    int n = blockIdx.x, d = threadIdx.x;
    float a = z1[(size_t)n * DMODEL + d];
    float b = z2[(size_t)n * DMODEL + d];
    float c = z3[(size_t)n * DMODEL + d];
    float gg = ln_g[d], bb = ln_b[d], pg = lnp_g[d], pb = lnp_b[d];
    size_t base = (size_t)n * KP;

    auto emit = [&](int seg, float v) {
        u16 h = f2bf(v);
        xhi[base + seg * DMODEL + d] = h;
        xlo[base + seg * DMODEL + d] = f2bf(v - bf2f(h));
    };
    float2 s;
    s = bstats512(a, d, red); float z1n = (a - s.x) * s.y * gg + bb;
    s = bstats512(b, d, red); float z2n = (b - s.x) * s.y * gg + bb;
    s = bstats512(c, d, red); float z3n = (c - s.x) * s.y * gg + bb;
    emit(0, z1n); emit(1, z2n); emit(2, z3n);
    auto pln = [&](int seg, float v) {
        float2 st = bstats512(v, d, red);
        emit(seg, (v - st.x) * st.y * pg + pb);
    };
    pln(3, z1n - z2n); pln(4, z1n - z3n); pln(5, z2n - z3n);
    pln(6, z1n * z2n); pln(7, z1n * z3n); pln(8, z2n * z3n);
    if (d < 64) {   // mask cols 4608..4610 + zero pad 4611..4671
        int col = 9 * DMODEL + d;
        float v = (d < 3) ? mask[(size_t)n * 3 + d] : 0.f;
        u16 h = f2bf(v);
        xhi[base + col] = h;
        xlo[base + col] = f2bf(v - bf2f(h));
    }
}

// ================= m97-style 128x128 bf16 MFMA GEMM bodies =================
// LDS tile: [128 rows][32 elems] unpadded (64 B rows). Staged by global_load_lds:
// wave w, instr i covers rows (w*2+i)*16 .. +16; lane l -> row +(l>>2), elems (l&3)*8.
// A/B-frag: [r=lane&15][k=(lane>>4)*8+j]; C/D: row=(lane>>4)*4+reg, col=lane&15.

#define GEMM_PREAMBLE                                                        \
    int t = threadIdx.x;                                                     \
    int lane = t & 63, w = t >> 6;                                           \
    int lrow = lane >> 2, lcol = (lane & 3) * 8;                             \
    int sr0 = (w * 2) * 16 + lrow, sr1 = (w * 2 + 1) * 16 + lrow;            \
    f32x4 acc[4][4];                                                         \
    { f32x4 z4 = {0.f, 0.f, 0.f, 0.f};                                       \
      _Pragma("unroll") for (int i = 0; i < 4; i++)                          \
      _Pragma("unroll") for (int j = 0; j < 4; j++) acc[i][j] = z4; }        \
    int wm = (w & 1) * 64, wn = (w >> 1) * 64;                               \
    int fr = lane & 15, fko = (lane >> 4) * 8;

#define GEMM_KSTEP                                                            \
        __syncthreads();                                                      \
        async_cp16(gA0, lA0); async_cp16(gA1, lA1);                           \
        async_cp16(gB0, lB0); async_cp16(gB1, lB1);                           \
        gA0 += BK; gA1 += BK; gB0 += BK; gB1 += BK;                           \
        __syncthreads();                                                      \
        bf16x8 af[4], bfr[4];                                                 \
        _Pragma("unroll") for (int i = 0; i < 4; i++)                         \
            af[i] = *(const bf16x8*)&lA[(wm + i * 16 + fr) * BK + fko];       \
        _Pragma("unroll") for (int j = 0; j < 4; j++)                         \
            bfr[j] = *(const bf16x8*)&lB[(wn + j * 16 + fr) * BK + fko];      \
        _Pragma("unroll") for (int i = 0; i < 4; i++)                         \
        _Pragma("unroll") for (int j = 0; j < 4; j++)                         \
            acc[i][j] = __builtin_amdgcn_mfma_f32_16x16x32_bf16(af[i], bfr[j], acc[i][j], 0, 0, 0);

// ---- router fc1: partial GEMM, part = region(3: hh,hl,lh) x k-half(2) ----
__global__ __launch_bounds__(256)
void router_fc1(const u16* __restrict__ xhi, const u16* __restrict__ xlo,
                const u16* __restrict__ rw1hi, const u16* __restrict__ rw1lo,
                float* __restrict__ rpart) {
    int mt = blockIdx.x, nt = blockIdx.y, part = blockIdx.z;
    int region = part >> 1, half = part & 1;
    const u16* A = (region == 2) ? xlo : xhi;        // hh: hi*hi, hl: hi*lo, lh: lo*hi
    const u16* B = (region == 1) ? rw1lo : rw1hi;
    int kbase = half * (KP / 2);

    __shared__ u16 lA[128 * BK];
    __shared__ u16 lB[128 * BK];
    GEMM_PREAMBLE

    const u16* gA0 = A + (size_t)(mt * 128 + sr0) * KP + kbase + lcol;
    const u16* gA1 = A + (size_t)(mt * 128 + sr1) * KP + kbase + lcol;
    const u16* gB0 = B + (size_t)(nt * 128 + sr0) * KP + kbase + lcol;
    const u16* gB1 = B + (size_t)(nt * 128 + sr1) * KP + kbase + lcol;
    u16* lA0 = &lA[(w * 2) * 16 * BK];
    u16* lA1 = &lA[(w * 2 + 1) * 16 * BK];
    u16* lB0 = &lB[(w * 2) * 16 * BK];
    u16* lB1 = &lB[(w * 2 + 1) * 16 * BK];

    for (int k0 = 0; k0 < KP / 2; k0 += BK) {
        GEMM_KSTEP
    }
    float* outp = rpart + (size_t)part * ((size_t)N_TOK * RHDIM);
    int q = lane >> 4, cn = lane & 15;
    #pragma unroll
    for (int i = 0; i < 4; i++)
        #pragma unroll
        for (int rr = 0; rr < 4; rr++) {
            int mg = mt * 128 + wm + i * 16 + q * 4 + rr;
            #pragma unroll
            for (int j = 0; j < 4; j++)
                outp[(size_t)mg * RHDIM + nt * 128 + wn + j * 16 + cn] = acc[i][j][rr];
        }
}

__global__ void router_act(const float* __restrict__ rpart, const float* __restrict__ r_b1,
                           float* __restrict__ rh) {
    int idx = blockIdx.x * 256 + threadIdx.x;
    float v = 0.f;
    #pragma unroll
    for (int p = 0; p < 6; p++) v += rpart[(size_t)p * ((size_t)N_TOK * RHDIM) + idx];
    v += r_b1[idx & (RHDIM - 1)];
    rh[idx] = gelu_exact(v);
}

// ---- logits + top-2 + gates + expert scatter: one wave per token ----
__global__ __launch_bounds__(256)
void logits_topk(const float* __restrict__ rh, const float* __restrict__ r_w2,
                 const float* __restrict__ r_b2, const float* __restrict__ log_temp,
                 float* __restrict__ pgate, int* __restrict__ pexp,
                 int* __restrict__ lists, int* __restrict__ counts) {
    int t = threadIdx.x, wave = t >> 6, lane = t & 63;
    int n = blockIdx.x * 4 + wave;
    int e = lane & 7, ch = lane >> 3;
    const float* r = rh + (size_t)n * RHDIM;
    float s = 0.f;
    #pragma unroll
    for (int k = 0; k < 32; k++) s += r[ch * 32 + k] * r_w2[(ch * 32 + k) * 8 + e];
    s += __shfl_xor(s, 8);
    s += __shfl_xor(s, 16);
    s += __shfl_xor(s, 32);
    float temp = fminf(fmaxf(expf(log_temp[0]), 1e-3f), 100.f);
    float logit = (s + r_b2[e]) / temp;
    float l[8];
    #pragma unroll
    for (int i = 0; i < 8; i++) l[i] = __shfl(logit, i);
    if (lane == 0) {
        int i1 = 0;
        #pragma unroll
        for (int i = 1; i < 8; i++) if (l[i] > l[i1]) i1 = i;   // first-occurrence max (matches top_k)
        int i2 = (i1 == 0) ? 1 : 0;
        #pragma unroll
        for (int i = 0; i < 8; i++) if (i != i1 && l[i] > l[i2]) i2 = i;
        float p = expf(l[i2] - l[i1]);
        float g1 = 1.f / (1.f + p);
        float g2 = p / (1.f + p);
        pgate[n * 2] = g1;     pexp[n * 2] = i1;
        pgate[n * 2 + 1] = g2; pexp[n * 2 + 1] = i2;
        int pos1 = atomicAdd(&counts[i1], 1);
        lists[(size_t)i1 * N_TOK + pos1] = n * 2;
        int pos2 = atomicAdd(&counts[i2], 1);
        lists[(size_t)i2 * N_TOK + pos2] = n * 2 + 1;
    }
}

// ---- expert fc1: gathered [cnt,KP] x [KP,H] bf16 GEMM, gelu epilogue -> eh bf16 ----
__global__ __launch_bounds__(256)
void expert_fc1(const u16* __restrict__ xhi, const u16* __restrict__ w1t,
                const float* __restrict__ e_b1, const int* __restrict__ lists,
                const int* __restrict__ counts, u16* __restrict__ eh) {
    int e = blockIdx.z, mt = blockIdx.x, nt = blockIdx.y;
    int cnt = counts[e];
    if (mt * 128 >= cnt) return;

    __shared__ u16 lA[128 * BK];
    __shared__ u16 lB[128 * BK];
    __shared__ int rows[128];
    int tt = threadIdx.x;
    if (tt < 128) {
        int m = mt * 128 + tt;
        rows[tt] = lists[(size_t)e * N_TOK + (m < cnt ? m : 0)];   // clamp tail to valid entry
    }
    __syncthreads();

    GEMM_PREAMBLE

    const u16* gA0 = xhi + (size_t)(rows[sr0] >> 1) * KP + lcol;
    const u16* gA1 = xhi + (size_t)(rows[sr1] >> 1) * KP + lcol;
    const u16* wb = w1t + (size_t)e * HEXP * KP + (size_t)(nt * 128) * KP;
    const u16* gB0 = wb + (size_t)sr0 * KP + lcol;
    const u16* gB1 = wb + (size_t)sr1 * KP + lcol;
    u16* lA0 = &lA[(w * 2) * 16 * BK];
    u16* lA1 = &lA[(w * 2 + 1) * 16 * BK];
    u16* lB0 = &lB[(w * 2) * 16 * BK];
    u16* lB1 = &lB[(w * 2 + 1) * 16 * BK];

    for (int k0 = 0; k0 < KP; k0 += BK) {
        GEMM_KSTEP
    }
    int q = lane >> 4, cn = lane & 15;
    #pragma unroll
    for (int i = 0; i < 4; i++)
        #pragma unroll
        for (int rr = 0; rr < 4; rr++) {
            int ml = wm + i * 16 + q * 4 + rr;
            int mg = mt * 128 + ml;
            if (mg < cnt) {
                int entry = rows[ml];
                #pragma unroll
                for (int j = 0; j < 4; j++) {
                    int col = nt * 128 + wn + j * 16 + cn;
                    float v = acc[i][j][rr] + e_b1[(size_t)e * HEXP + col];
                    eh[(size_t)entry * HEXP + col] = f2bf(gelu_exact(v));
                }
            }
        }
}

// ---- expert fc2: gathered [cnt,H] x [H,D] bf16 GEMM -> per-slot fp32 outs ----
__global__ __launch_bounds__(256)
void expert_fc2(const u16* __restrict__ eh, const u16* __restrict__ w2t,
                const int* __restrict__ lists, const int* __restrict__ counts,
                float* __restrict__ outs) {
    int e = blockIdx.z, mt = blockIdx.x, nt = blockIdx.y;
    int cnt = counts[e];
    if (mt * 128 >= cnt) return;

    __shared__ u16 lA[128 * BK];
    __shared__ u16 lB[128 * BK];
    __shared__ int rows[128];
    int tt = threadIdx.x;
    if (tt < 128) {
        int m = mt * 128 + tt;
        rows[tt] = lists[(size_t)e * N_TOK + (m < cnt ? m : 0)];
    }
    __syncthreads();

    GEMM_PREAMBLE

    const u16* gA0 = eh + (size_t)rows[sr0] * HEXP + lcol;
    const u16* gA1 = eh + (size_t)rows[sr1] * HEXP + lcol;
    const u16* wb = w2t + (size_t)e * DMODEL * HEXP + (size_t)(nt * 128) * HEXP;
    const u16* gB0 = wb + (size_t)sr0 * HEXP + lcol;
    const u16* gB1 = wb + (size_t)sr1 * HEXP + lcol;
    u16* lA0 = &lA[(w * 2) * 16 * BK];
    u16* lA1 = &lA[(w * 2 + 1) * 16 * BK];
    u16* lB0 = &lB[(w * 2) * 16 * BK];
    u16* lB1 = &lB[(w * 2 + 1) * 16 * BK];

    for (int k0 = 0; k0 < HEXP; k0 += BK) {
        GEMM_KSTEP
    }
    int q = lane >> 4, cn = lane & 15;
    #pragma unroll
    for (int i = 0; i < 4; i++)
        #pragma unroll
        for (int rr = 0; rr < 4; rr++) {
            int ml = wm + i * 16 + q * 4 + rr;
            int mg = mt * 128 + ml;
            if (mg < cnt) {
                int entry = rows[ml];
                #pragma unroll
                for (int j = 0; j < 4; j++) {
                    int col = nt * 128 + wn + j * 16 + cn;
                    outs[(size_t)entry * DMODEL + col] = acc[i][j][rr];
                }
            }
        }
}

// ---- combine: gate*(outs+b2) + masked residual + final LN ----
__global__ __launch_bounds__(512)
void combine_ln(const float* __restrict__ outs, const float* __restrict__ pgate,
                const int* __restrict__ pexp, const float* __restrict__ e_b2,
                const float* __restrict__ mask, const u16* __restrict__ xhi,
                const u16* __restrict__ xlo, const float* __restrict__ oln_g,
                const float* __restrict__ oln_b, float* __restrict__ out) {
    __shared__ float red[18];
    int n = blockIdx.x, d = threadIdx.x;
    float g0 = pgate[n * 2], g1 = pgate[n * 2 + 1];
    int e0 = pexp[n * 2], e1 = pexp[n * 2 + 1];
    float o = g0 * (outs[(size_t)(n * 2) * DMODEL + d] + e_b2[(size_t)e0 * DMODEL + d])
            + g1 * (outs[(size_t)(n * 2 + 1) * DMODEL + d] + e_b2[(size_t)e1 * DMODEL + d]);
    float m0 = mask[n * 3 + 0], m1 = mask[n * 3 + 1], m2 = mask[n * 3 + 2];
    float denom = fmaxf(m0 + m1 + m2, 1.f);
    size_t xb = (size_t)n * KP;
    float z1n = bf2f(xhi[xb + d]) + bf2f(xlo[xb + d]);                       // hi+lo = fp32-exact
    float z2n = bf2f(xhi[xb + DMODEL + d]) + bf2f(xlo[xb + DMODEL + d]);
    float z3n = bf2f(xhi[xb + 2 * DMODEL + d]) + bf2f(xlo[xb + 2 * DMODEL + d]);
    float z = o + (m0 * z1n + m1 * z2n + m2 * z3n) / denom;
    float2 st = bstats512(z, d, red);
    out[(size_t)n * DMODEL + d] = (z - st.x) * st.y * oln_g[d] + oln_b[d];
}

extern "C" void kernel_launch(void* const* d_in, const int* in_sizes, int n_in,
                              void* d_out, int out_size, void* d_ws, size_t ws_size,
                              hipStream_t stream) {
    (void)in_sizes; (void)n_in; (void)out_size; (void)ws_size;
    const float* z1       = (const float*)d_in[0];
    const float* z2       = (const float*)d_in[1];
    const float* z3       = (const float*)d_in[2];
    const float* mask     = (const float*)d_in[3];
    const float* ln_g     = (const float*)d_in[4];
    const float* ln_b     = (const float*)d_in[5];
    const float* lnp_g    = (const float*)d_in[6];
    const float* lnp_b    = (const float*)d_in[7];
    const float* oln_g    = (const float*)d_in[8];
    const float* oln_b    = (const float*)d_in[9];
    const float* r_w1     = (const float*)d_in[10];
    const float* r_b1     = (const float*)d_in[11];
    const float* r_w2     = (const float*)d_in[12];
    const float* r_b2     = (const float*)d_in[13];
    const float* log_temp = (const float*)d_in[14];
    const float* e_w1     = (const float*)d_in[15];
    const float* e_b1     = (const float*)d_in[16];
    const float* e_w2     = (const float*)d_in[17];
    const float* e_b2     = (const float*)d_in[18];
    float* out = (float*)d_out;

    char* p = (char*)d_ws;
    auto carve = [&](size_t bytes) { char* r = p; p += (bytes + 255) & ~(size_t)255; return r; };
    u16*   xhi    = (u16*)carve((size_t)N_TOK * KP * 2);
    u16*   xlo    = (u16*)carve((size_t)N_TOK * KP * 2);
    u16*   w1t    = (u16*)carve((size_t)NEXP * HEXP * KP * 2);
    u16*   w2t    = (u16*)carve((size_t)NEXP * DMODEL * HEXP * 2);
    u16*   rw1hi  = (u16*)carve((size_t)RHDIM * KP * 2);
    u16*   rw1lo  = (u16*)carve((size_t)RHDIM * KP * 2);
    float* rpart  = (float*)carve((size_t)6 * N_TOK * RHDIM * 4);
    float* rh     = (float*)carve((size_t)N_TOK * RHDIM * 4);
    u16*   eh     = (u16*)carve((size_t)NPAIR * HEXP * 2);
    float* outsb  = (float*)carve((size_t)NPAIR * DMODEL * 4);
    float* pgate  = (float*)carve((size_t)NPAIR * 4);
    int*   pexp   = (int*)carve((size_t)NPAIR * 4);
    int*   lists  = (int*)carve((size_t)NEXP * N_TOK * 4);
    int*   counts = (int*)carve(256);

    dim3 tb(32, 8);
    transpose_f32_bf16<<<dim3(KP / 32, HEXP / 32, NEXP), tb, 0, stream>>>(
        e_w1, w1t, (u16*)nullptr, IN_REAL, KP, HEXP, (size_t)IN_REAL * HEXP, (size_t)HEXP * KP);
    transpose_f32_bf16<<<dim3(HEXP / 32, DMODEL / 32, NEXP), tb, 0, stream>>>(
        e_w2, w2t, (u16*)nullptr, HEXP, HEXP, DMODEL, (size_t)HEXP * DMODEL, (size_t)DMODEL * HEXP);
    transpose_f32_bf16<<<dim3(KP / 32, RHDIM / 32, 1), tb, 0, stream>>>(
        r_w1, rw1hi, rw1lo, IN_REAL, KP, RHDIM, (size_t)0, (size_t)0);

    build_x<<<N_TOK, 512, 0, stream>>>(z1, z2, z3, mask, ln_g, ln_b, lnp_g, lnp_b, xhi, xlo);

    router_fc1<<<dim3(64, 2, 6), 256, 0, stream>>>(xhi, xlo, rw1hi, rw1lo, rpart);
    router_act<<<(N_TOK * RHDIM) / 256, 256, 0, stream>>>(rpart, r_b1, rh);

    hipMemsetAsync(counts, 0, 256, stream);
    logits_topk<<<N_TOK / 4, 256, 0, stream>>>(rh, r_w2, r_b2, log_temp, pgate, pexp, lists, counts);

    expert_fc1<<<dim3(64, HEXP / 128, NEXP), 256, 0, stream>>>(xhi, w1t, e_b1, lists, counts, eh);
    expert_fc2<<<dim3(64, DMODEL / 128, NEXP), 256, 0, stream>>>(eh, w2t, lists, counts, outsb);

    combine_ln<<<N_TOK, 512, 0, stream>>>(outsb, pgate, pexp, e_b2, mask, xhi, xlo, oln_g, oln_b, out);
}

// Round 3
// 1175.392 us; speedup vs baseline: 1.1456x; 1.0800x over previous
//
#include <hip/hip_runtime.h>
#include <math.h>

#define N_TOK 8192
#define DMODEL 512
#define NEXP 8
#define HEXP 1024
#define RHDIM 256
#define KP 4672          // IN_DIM=4611 padded to multiple of 64 (zero-filled); KP*2B = 73 cache lines
#define IN_REAL 4611
#define BK 64            // K-tile; one LDS row = 128 B = exactly one cache line
#define NPAIR (N_TOK * 2)

typedef unsigned short u16;
typedef __bf16 bf16x8 __attribute__((ext_vector_type(8)));
typedef float f32x4 __attribute__((ext_vector_type(4)));

__device__ inline u16 f2bf(float f) {
    union { float f; unsigned u; } x; x.f = f;
    unsigned r = x.u + 0x7FFFu + ((x.u >> 16) & 1u);   // round-to-nearest-even
    return (u16)(r >> 16);
}
__device__ inline float bf2f(u16 u) {
    union { unsigned u; float f; } x; x.u = ((unsigned)u) << 16;
    return x.f;
}
__device__ inline float gelu_exact(float v) {
    return 0.5f * v * (1.f + erff(v * 0.70710678118654752440f));
}

// async global->LDS, 16B per lane; lds base wave-uniform, lane lands at base + lane*16
__device__ inline void async_cp16(const u16* g, u16* l) {
    __builtin_amdgcn_global_load_lds(
        (const __attribute__((address_space(1))) unsigned int*)g,
        (__attribute__((address_space(3))) unsigned int*)l, 16, 0, 0);
}

// ---- block stats for 512-thread blocks: returns (mean, rsqrt(var+eps)) ----
__device__ inline float2 bstats512(float v, int tid, float* red) {
    float s = v, q = v * v;
    #pragma unroll
    for (int o = 32; o > 0; o >>= 1) {
        s += __shfl_xor(s, o);
        q += __shfl_xor(q, o);
    }
    __syncthreads();
    if ((tid & 63) == 0) { red[(tid >> 6) * 2] = s; red[(tid >> 6) * 2 + 1] = q; }
    __syncthreads();
    if (tid == 0) {
        float S = 0.f, Q = 0.f;
        #pragma unroll
        for (int i = 0; i < 8; i++) { S += red[i * 2]; Q += red[i * 2 + 1]; }
        float m = S * (1.f / 512.f);
        float var = fmaxf(Q * (1.f / 512.f) - m * m, 0.f);
        red[16] = m;
        red[17] = rsqrtf(var + 1e-5f);
    }
    __syncthreads();
    return make_float2(red[16], red[17]);
}

// ---- transpose fp32 [K0,H] -> bf16 [H,KPd] (zero-fill k>=K0), optional hi/lo split ----
__global__ __launch_bounds__(256)
void transpose_f32_bf16(const float* __restrict__ src, u16* __restrict__ dhi, u16* __restrict__ dlo,
                        int K0, int KPd, int H, size_t sbatch, size_t dbatch) {
    __shared__ float tile[32][33];
    int bz = blockIdx.z;
    src += (size_t)bz * sbatch;
    size_t dob = (size_t)bz * dbatch;
    int k0 = blockIdx.x * 32, h0 = blockIdx.y * 32;
    int tx = threadIdx.x, ty = threadIdx.y;
    for (int i = ty; i < 32; i += 8) {
        int k = k0 + i;
        tile[i][tx] = (k < K0) ? src[(size_t)k * H + (h0 + tx)] : 0.f;
    }
    __syncthreads();
    for (int i = ty; i < 32; i += 8) {
        int h = h0 + i, k = k0 + tx;
        float v = tile[tx][i];
        u16 hv = f2bf(v);
        dhi[dob + (size_t)h * KPd + k] = hv;
        if (dlo) dlo[dob + (size_t)h * KPd + k] = f2bf(v - bf2f(hv));
    }
}

// ---- build fusion input x (9 LayerNorms + mask), emit bf16 hi/lo split ----
__global__ __launch_bounds__(512)
void build_x(const float* __restrict__ z1, const float* __restrict__ z2, const float* __restrict__ z3,
             const float* __restrict__ mask,
             const float* __restrict__ ln_g, const float* __restrict__ ln_b,
             const float* __restrict__ lnp_g, const float* __restrict__ lnp_b,
             u16* __restrict__ xhi, u16* __restrict__ xlo) {
    __shared__ float red[18];
    int n = blockIdx.x, d = threadIdx.x;
    float a = z1[(size_t)n * DMODEL + d];
    float b = z2[(size_t)n * DMODEL + d];
    float c = z3[(size_t)n * DMODEL + d];
    float gg = ln_g[d], bb = ln_b[d], pg = lnp_g[d], pb = lnp_b[d];
    size_t base = (size_t)n * KP;

    auto emit = [&](int seg, float v) {
        u16 h = f2bf(v);
        xhi[base + seg * DMODEL + d] = h;
        xlo[base + seg * DMODEL + d] = f2bf(v - bf2f(h));
    };
    float2 s;
    s = bstats512(a, d, red); float z1n = (a - s.x) * s.y * gg + bb;
    s = bstats512(b, d, red); float z2n = (b - s.x) * s.y * gg + bb;
    s = bstats512(c, d, red); float z3n = (c - s.x) * s.y * gg + bb;
    emit(0, z1n); emit(1, z2n); emit(2, z3n);
    auto pln = [&](int seg, float v) {
        float2 st = bstats512(v, d, red);
        emit(seg, (v - st.x) * st.y * pg + pb);
    };
    pln(3, z1n - z2n); pln(4, z1n - z3n); pln(5, z2n - z3n);
    pln(6, z1n * z2n); pln(7, z1n * z3n); pln(8, z2n * z3n);
    if (d < 64) {   // mask cols 4608..4610 + zero pad 4611..4671
        int col = 9 * DMODEL + d;
        float v = (d < 3) ? mask[(size_t)n * 3 + d] : 0.f;
        u16 h = f2bf(v);
        xhi[base + col] = h;
        xlo[base + col] = f2bf(v - bf2f(h));
    }
}

// ================= 128x256 (BMxBN) bf16 MFMA GEMM, BK=64, 512 threads =================
// LDS rows are 64 elems = 128 B = one cache line. XOR swizzle: LDS chunk c holds global
// chunk c ^ (row&7); staging picks global chunk ((lane&7)^(lane>>3 &7)), fragment reads
// chunk (q ^ (fr&7)). Wave grid: wm=(w&1)*64, wn=(w>>1)*64; per-wave 64x64, acc[4][4].
// A/B-frag: [r=lane&15][k=(lane>>4)*8+j]; C/D: row=(lane>>4)*4+reg, col=lane&15.

#define GEMM_DEFS                                                             \
    int t = threadIdx.x;                                                      \
    int lane = t & 63, w = t >> 6;                                            \
    int r8 = lane >> 3;                                                       \
    int ce = ((lane & 7) ^ r8) * 8;       /* swizzled global chunk, elems */  \
    int fr = lane & 15, q4 = lane >> 4;                                       \
    int wm = (w & 1) * 64, wn = (w >> 1) * 64;                                \
    f32x4 acc[4][4];                                                          \
    { f32x4 z4 = {0.f, 0.f, 0.f, 0.f};                                        \
      _Pragma("unroll") for (int i = 0; i < 4; i++)                           \
      _Pragma("unroll") for (int j = 0; j < 4; j++) acc[i][j] = z4; }         \
    u16* lA0 = lA + (w * 16) * BK;                                            \
    u16* lA1 = lA + (w * 16 + 8) * BK;                                        \
    u16* lB0 = lB + (w * 32) * BK;                                            \
    u16* lB1 = lB + (w * 32 + 8) * BK;                                        \
    u16* lB2 = lB + (w * 32 + 16) * BK;                                       \
    u16* lB3 = lB + (w * 32 + 24) * BK;

#define GEMM_KSTEP                                                            \
        __syncthreads();                                                      \
        async_cp16(gA0, lA0); async_cp16(gA1, lA1);                           \
        async_cp16(gB0, lB0); async_cp16(gB1, lB1);                           \
        async_cp16(gB2, lB2); async_cp16(gB3, lB3);                           \
        gA0 += BK; gA1 += BK; gB0 += BK; gB1 += BK; gB2 += BK; gB3 += BK;     \
        __syncthreads();                                                      \
        _Pragma("unroll") for (int ks = 0; ks < 2; ks++) {                    \
            bf16x8 af[4], bfr[4];                                             \
            int cofs = (((q4 + ks * 4) ^ (fr & 7)) * 8);                      \
            _Pragma("unroll") for (int i = 0; i < 4; i++)                     \
                af[i] = *(const bf16x8*)&lA[(wm + i * 16 + fr) * BK + cofs];  \
            _Pragma("unroll") for (int j = 0; j < 4; j++)                     \
                bfr[j] = *(const bf16x8*)&lB[(wn + j * 16 + fr) * BK + cofs]; \
            _Pragma("unroll") for (int i = 0; i < 4; i++)                     \
            _Pragma("unroll") for (int j = 0; j < 4; j++)                     \
                acc[i][j] = __builtin_amdgcn_mfma_f32_16x16x32_bf16(af[i], bfr[j], acc[i][j], 0, 0, 0); \
        }

// ---- router fc1: partial GEMM; grid (mt=64, part=6); part = region*2 + khalf ----
__global__ __launch_bounds__(512, 4)
void router_fc1(const u16* __restrict__ xhi, const u16* __restrict__ xlo,
                const u16* __restrict__ rw1hi, const u16* __restrict__ rw1lo,
                float* __restrict__ rpart) {
    int mt = blockIdx.x, part = blockIdx.y;
    int region = part >> 1, half = part & 1;
    const u16* A = (region == 2) ? xlo : xhi;        // hh: hi*hi, hl: hi*lo, lh: lo*hi
    const u16* B = (region == 1) ? rw1lo : rw1hi;
    int kbase = half ? 2304 : 0;
    int klen  = half ? 2368 : 2304;                  // both divisible by 64

    __shared__ u16 lA[128 * BK];
    __shared__ u16 lB[256 * BK];
    GEMM_DEFS

    const u16* gA0 = A + (size_t)(mt * 128 + w * 16 + r8) * KP + kbase + ce;
    const u16* gA1 = A + (size_t)(mt * 128 + w * 16 + 8 + r8) * KP + kbase + ce;
    const u16* gB0 = B + (size_t)(w * 32 + r8) * KP + kbase + ce;
    const u16* gB1 = B + (size_t)(w * 32 + 8 + r8) * KP + kbase + ce;
    const u16* gB2 = B + (size_t)(w * 32 + 16 + r8) * KP + kbase + ce;
    const u16* gB3 = B + (size_t)(w * 32 + 24 + r8) * KP + kbase + ce;

    for (int k0 = 0; k0 < klen; k0 += BK) {
        GEMM_KSTEP
    }
    float* outp = rpart + (size_t)part * ((size_t)N_TOK * RHDIM);
    int cn = lane & 15;
    #pragma unroll
    for (int i = 0; i < 4; i++)
        #pragma unroll
        for (int rr = 0; rr < 4; rr++) {
            int mg = mt * 128 + wm + i * 16 + q4 * 4 + rr;
            #pragma unroll
            for (int j = 0; j < 4; j++)
                outp[(size_t)mg * RHDIM + wn + j * 16 + cn] = acc[i][j][rr];
        }
}

__global__ void router_act(const float* __restrict__ rpart, const float* __restrict__ r_b1,
                           float* __restrict__ rh) {
    int idx = blockIdx.x * 256 + threadIdx.x;
    float v = 0.f;
    #pragma unroll
    for (int p = 0; p < 6; p++) v += rpart[(size_t)p * ((size_t)N_TOK * RHDIM) + idx];
    v += r_b1[idx & (RHDIM - 1)];
    rh[idx] = gelu_exact(v);
}

// ---- logits + top-2 + gates + expert scatter: one wave per token ----
__global__ __launch_bounds__(256)
void logits_topk(const float* __restrict__ rh, const float* __restrict__ r_w2,
                 const float* __restrict__ r_b2, const float* __restrict__ log_temp,
                 float* __restrict__ pgate, int* __restrict__ pexp,
                 int* __restrict__ lists, int* __restrict__ counts) {
    int t = threadIdx.x, wave = t >> 6, lane = t & 63;
    int n = blockIdx.x * 4 + wave;
    int e = lane & 7, ch = lane >> 3;
    const float* r = rh + (size_t)n * RHDIM;
    float s = 0.f;
    #pragma unroll
    for (int k = 0; k < 32; k++) s += r[ch * 32 + k] * r_w2[(ch * 32 + k) * 8 + e];
    s += __shfl_xor(s, 8);
    s += __shfl_xor(s, 16);
    s += __shfl_xor(s, 32);
    float temp = fminf(fmaxf(expf(log_temp[0]), 1e-3f), 100.f);
    float logit = (s + r_b2[e]) / temp;
    float l[8];
    #pragma unroll
    for (int i = 0; i < 8; i++) l[i] = __shfl(logit, i);
    if (lane == 0) {
        int i1 = 0;
        #pragma unroll
        for (int i = 1; i < 8; i++) if (l[i] > l[i1]) i1 = i;   // first-occurrence max (matches top_k)
        int i2 = (i1 == 0) ? 1 : 0;
        #pragma unroll
        for (int i = 0; i < 8; i++) if (i != i1 && l[i] > l[i2]) i2 = i;
        float p = expf(l[i2] - l[i1]);
        float g1 = 1.f / (1.f + p);
        float g2 = p / (1.f + p);
        pgate[n * 2] = g1;     pexp[n * 2] = i1;
        pgate[n * 2 + 1] = g2; pexp[n * 2 + 1] = i2;
        int pos1 = atomicAdd(&counts[i1], 1);
        lists[(size_t)i1 * N_TOK + pos1] = n * 2;
        int pos2 = atomicAdd(&counts[i2], 1);
        lists[(size_t)i2 * N_TOK + pos2] = n * 2 + 1;
    }
}

// ---- expert fc1: gathered [cnt,KP] x [KP,1024] bf16 GEMM, gelu -> eh bf16 ----
// grid x = nt*8 + e (32) so linear%8==e pins each expert to one XCD; y = mt
__global__ __launch_bounds__(512, 4)
void expert_fc1(const u16* __restrict__ xhi, const u16* __restrict__ w1t,
                const float* __restrict__ e_b1, const int* __restrict__ lists,
                const int* __restrict__ counts, u16* __restrict__ eh) {
    int e = blockIdx.x & 7, nt = blockIdx.x >> 3, mt = blockIdx.y;
    int cnt = counts[e];
    if (mt * 128 >= cnt) return;

    __shared__ u16 lA[128 * BK];
    __shared__ u16 lB[256 * BK];
    __shared__ int rows[128];
    int tt = threadIdx.x;
    if (tt < 128) {
        int m = mt * 128 + tt;
        rows[tt] = lists[(size_t)e * N_TOK + (m < cnt ? m : 0)];   // clamp tail to valid entry
    }
    __syncthreads();

    GEMM_DEFS

    const u16* gA0 = xhi + (size_t)(rows[w * 16 + r8] >> 1) * KP + ce;
    const u16* gA1 = xhi + (size_t)(rows[w * 16 + 8 + r8] >> 1) * KP + ce;
    const u16* wb = w1t + (size_t)e * HEXP * KP + (size_t)(nt * 256) * KP;
    const u16* gB0 = wb + (size_t)(w * 32 + r8) * KP + ce;
    const u16* gB1 = wb + (size_t)(w * 32 + 8 + r8) * KP + ce;
    const u16* gB2 = wb + (size_t)(w * 32 + 16 + r8) * KP + ce;
    const u16* gB3 = wb + (size_t)(w * 32 + 24 + r8) * KP + ce;

    for (int k0 = 0; k0 < KP; k0 += BK) {
        GEMM_KSTEP
    }
    int cn = lane & 15;
    #pragma unroll
    for (int i = 0; i < 4; i++)
        #pragma unroll
        for (int rr = 0; rr < 4; rr++) {
            int ml = wm + i * 16 + q4 * 4 + rr;
            int mg = mt * 128 + ml;
            if (mg < cnt) {
                int entry = rows[ml];
                #pragma unroll
                for (int j = 0; j < 4; j++) {
                    int col = nt * 256 + wn + j * 16 + cn;
                    float v = acc[i][j][rr] + e_b1[(size_t)e * HEXP + col];
                    eh[(size_t)entry * HEXP + col] = f2bf(gelu_exact(v));
                }
            }
        }
}

// ---- expert fc2: gathered [cnt,1024] x [1024,512] bf16 GEMM -> per-slot fp32 outs ----
__global__ __launch_bounds__(512, 4)
void expert_fc2(const u16* __restrict__ eh, const u16* __restrict__ w2t,
                const int* __restrict__ lists, const int* __restrict__ counts,
                float* __restrict__ outs) {
    int e = blockIdx.x & 7, nt = blockIdx.x >> 3, mt = blockIdx.y;
    int cnt = counts[e];
    if (mt * 128 >= cnt) return;

    __shared__ u16 lA[128 * BK];
    __shared__ u16 lB[256 * BK];
    __shared__ int rows[128];
    int tt = threadIdx.x;
    if (tt < 128) {
        int m = mt * 128 + tt;
        rows[tt] = lists[(size_t)e * N_TOK + (m < cnt ? m : 0)];
    }
    __syncthreads();

    GEMM_DEFS

    const u16* gA0 = eh + (size_t)rows[w * 16 + r8] * HEXP + ce;
    const u16* gA1 = eh + (size_t)rows[w * 16 + 8 + r8] * HEXP + ce;
    const u16* wb = w2t + (size_t)e * DMODEL * HEXP + (size_t)(nt * 256) * HEXP;
    const u16* gB0 = wb + (size_t)(w * 32 + r8) * HEXP + ce;
    const u16* gB1 = wb + (size_t)(w * 32 + 8 + r8) * HEXP + ce;
    const u16* gB2 = wb + (size_t)(w * 32 + 16 + r8) * HEXP + ce;
    const u16* gB3 = wb + (size_t)(w * 32 + 24 + r8) * HEXP + ce;

    for (int k0 = 0; k0 < HEXP; k0 += BK) {
        GEMM_KSTEP
    }
    int cn = lane & 15;
    #pragma unroll
    for (int i = 0; i < 4; i++)
        #pragma unroll
        for (int rr = 0; rr < 4; rr++) {
            int ml = wm + i * 16 + q4 * 4 + rr;
            int mg = mt * 128 + ml;
            if (mg < cnt) {
                int entry = rows[ml];
                #pragma unroll
                for (int j = 0; j < 4; j++) {
                    int col = nt * 256 + wn + j * 16 + cn;
                    outs[(size_t)entry * DMODEL + col] = acc[i][j][rr];
                }
            }
        }
}

// ---- combine: gate*(outs+b2) + masked residual + final LN ----
__global__ __launch_bounds__(512)
void combine_ln(const float* __restrict__ outs, const float* __restrict__ pgate,
                const int* __restrict__ pexp, const float* __restrict__ e_b2,
                const float* __restrict__ mask, const u16* __restrict__ xhi,
                const u16* __restrict__ xlo, const float* __restrict__ oln_g,
                const float* __restrict__ oln_b, float* __restrict__ out) {
    __shared__ float red[18];
    int n = blockIdx.x, d = threadIdx.x;
    float g0 = pgate[n * 2], g1 = pgate[n * 2 + 1];
    int e0 = pexp[n * 2], e1 = pexp[n * 2 + 1];
    float o = g0 * (outs[(size_t)(n * 2) * DMODEL + d] + e_b2[(size_t)e0 * DMODEL + d])
            + g1 * (outs[(size_t)(n * 2 + 1) * DMODEL + d] + e_b2[(size_t)e1 * DMODEL + d]);
    float m0 = mask[n * 3 + 0], m1 = mask[n * 3 + 1], m2 = mask[n * 3 + 2];
    float denom = fmaxf(m0 + m1 + m2, 1.f);
    size_t xb = (size_t)n * KP;
    float z1n = bf2f(xhi[xb + d]) + bf2f(xlo[xb + d]);                       // hi+lo = fp32-exact
    float z2n = bf2f(xhi[xb + DMODEL + d]) + bf2f(xlo[xb + DMODEL + d]);
    float z3n = bf2f(xhi[xb + 2 * DMODEL + d]) + bf2f(xlo[xb + 2 * DMODEL + d]);
    float z = o + (m0 * z1n + m1 * z2n + m2 * z3n) / denom;
    float2 st = bstats512(z, d, red);
    out[(size_t)n * DMODEL + d] = (z - st.x) * st.y * oln_g[d] + oln_b[d];
}

extern "C" void kernel_launch(void* const* d_in, const int* in_sizes, int n_in,
                              void* d_out, int out_size, void* d_ws, size_t ws_size,
                              hipStream_t stream) {
    (void)in_sizes; (void)n_in; (void)out_size; (void)ws_size;
    const float* z1       = (const float*)d_in[0];
    const float* z2       = (const float*)d_in[1];
    const float* z3       = (const float*)d_in[2];
    const float* mask     = (const float*)d_in[3];
    const float* ln_g     = (const float*)d_in[4];
    const float* ln_b     = (const float*)d_in[5];
    const float* lnp_g    = (const float*)d_in[6];
    const float* lnp_b    = (const float*)d_in[7];
    const float* oln_g    = (const float*)d_in[8];
    const float* oln_b    = (const float*)d_in[9];
    const float* r_w1     = (const float*)d_in[10];
    const float* r_b1     = (const float*)d_in[11];
    const float* r_w2     = (const float*)d_in[12];
    const float* r_b2     = (const float*)d_in[13];
    const float* log_temp = (const float*)d_in[14];
    const float* e_w1     = (const float*)d_in[15];
    const float* e_b1     = (const float*)d_in[16];
    const float* e_w2     = (const float*)d_in[17];
    const float* e_b2     = (const float*)d_in[18];
    float* out = (float*)d_out;

    char* p = (char*)d_ws;
    auto carve = [&](size_t bytes) { char* r = p; p += (bytes + 255) & ~(size_t)255; return r; };
    u16*   xhi    = (u16*)carve((size_t)N_TOK * KP * 2);
    u16*   xlo    = (u16*)carve((size_t)N_TOK * KP * 2);
    u16*   w1t    = (u16*)carve((size_t)NEXP * HEXP * KP * 2);
    u16*   w2t    = (u16*)carve((size_t)NEXP * DMODEL * HEXP * 2);
    u16*   rw1hi  = (u16*)carve((size_t)RHDIM * KP * 2);
    u16*   rw1lo  = (u16*)carve((size_t)RHDIM * KP * 2);
    float* rpart  = (float*)carve((size_t)6 * N_TOK * RHDIM * 4);
    float* rh     = (float*)carve((size_t)N_TOK * RHDIM * 4);
    u16*   eh     = (u16*)carve((size_t)NPAIR * HEXP * 2);
    float* outsb  = (float*)carve((size_t)NPAIR * DMODEL * 4);
    float* pgate  = (float*)carve((size_t)NPAIR * 4);
    int*   pexp   = (int*)carve((size_t)NPAIR * 4);
    int*   lists  = (int*)carve((size_t)NEXP * N_TOK * 4);
    int*   counts = (int*)carve(256);

    dim3 tb(32, 8);
    transpose_f32_bf16<<<dim3(KP / 32, HEXP / 32, NEXP), tb, 0, stream>>>(
        e_w1, w1t, (u16*)nullptr, IN_REAL, KP, HEXP, (size_t)IN_REAL * HEXP, (size_t)HEXP * KP);
    transpose_f32_bf16<<<dim3(HEXP / 32, DMODEL / 32, NEXP), tb, 0, stream>>>(
        e_w2, w2t, (u16*)nullptr, HEXP, HEXP, DMODEL, (size_t)HEXP * DMODEL, (size_t)DMODEL * HEXP);
    transpose_f32_bf16<<<dim3(KP / 32, RHDIM / 32, 1), tb, 0, stream>>>(
        r_w1, rw1hi, rw1lo, IN_REAL, KP, RHDIM, (size_t)0, (size_t)0);

    build_x<<<N_TOK, 512, 0, stream>>>(z1, z2, z3, mask, ln_g, ln_b, lnp_g, lnp_b, xhi, xlo);

    router_fc1<<<dim3(64, 6), 512, 0, stream>>>(xhi, xlo, rw1hi, rw1lo, rpart);
    router_act<<<(N_TOK * RHDIM) / 256, 256, 0, stream>>>(rpart, r_b1, rh);

    hipMemsetAsync(counts, 0, 256, stream);
    logits_topk<<<N_TOK / 4, 256, 0, stream>>>(rh, r_w2, r_b2, log_temp, pgate, pexp, lists, counts);

    expert_fc1<<<dim3(32, 64), 512, 0, stream>>>(xhi, w1t, e_b1, lists, counts, eh);
    expert_fc2<<<dim3(16, 64), 512, 0, stream>>>(eh, w2t, lists, counts, outsb);

    combine_ln<<<N_TOK, 512, 0, stream>>>(outsb, pgate, pexp, e_b2, mask, xhi, xlo, oln_g, oln_b, out);
}

// Round 4
// 1042.754 us; speedup vs baseline: 1.2913x; 1.1272x over previous
//
#include <hip/hip_runtime.h>
#include <math.h>

#define N_TOK 8192
#define DMODEL 512
#define NEXP 8
#define HEXP 1024
#define RHDIM 256
#define KP 4672          // IN_DIM=4611 padded to multiple of 64 (zero-filled); KP*2B = 73 cache lines
#define IN_REAL 4611
#define BK 64            // K-tile; one LDS row = 128 B = exactly one cache line
#define NPAIR (N_TOK * 2)
#define MAXT 136         // max expert tiles: 16384/128 + 8 rounding

typedef unsigned short u16;
typedef __bf16 bf16x8 __attribute__((ext_vector_type(8)));
typedef float f32x4 __attribute__((ext_vector_type(4)));

__device__ inline u16 f2bf(float f) {
    union { float f; unsigned u; } x; x.f = f;
    unsigned r = x.u + 0x7FFFu + ((x.u >> 16) & 1u);   // round-to-nearest-even
    return (u16)(r >> 16);
}
__device__ inline float bf2f(u16 u) {
    union { unsigned u; float f; } x; x.u = ((unsigned)u) << 16;
    return x.f;
}
__device__ inline float gelu_exact(float v) {
    return 0.5f * v * (1.f + erff(v * 0.70710678118654752440f));
}

// async global->LDS, 16B per lane; lds base wave-uniform, lane lands at base + lane*16
__device__ inline void async_cp16(const u16* g, u16* l) {
    __builtin_amdgcn_global_load_lds(
        (const __attribute__((address_space(1))) unsigned int*)g,
        (__attribute__((address_space(3))) unsigned int*)l, 16, 0, 0);
}

// ---- block stats for 512-thread blocks: returns (mean, rsqrt(var+eps)) ----
__device__ inline float2 bstats512(float v, int tid, float* red) {
    float s = v, q = v * v;
    #pragma unroll
    for (int o = 32; o > 0; o >>= 1) {
        s += __shfl_xor(s, o);
        q += __shfl_xor(q, o);
    }
    __syncthreads();
    if ((tid & 63) == 0) { red[(tid >> 6) * 2] = s; red[(tid >> 6) * 2 + 1] = q; }
    __syncthreads();
    if (tid == 0) {
        float S = 0.f, Q = 0.f;
        #pragma unroll
        for (int i = 0; i < 8; i++) { S += red[i * 2]; Q += red[i * 2 + 1]; }
        float m = S * (1.f / 512.f);
        float var = fmaxf(Q * (1.f / 512.f) - m * m, 0.f);
        red[16] = m;
        red[17] = rsqrtf(var + 1e-5f);
    }
    __syncthreads();
    return make_float2(red[16], red[17]);
}

// ---- transpose fp32 [K0,H] -> bf16 [H,KPd] (zero-fill k>=K0), optional hi/lo split ----
__global__ __launch_bounds__(256)
void transpose_f32_bf16(const float* __restrict__ src, u16* __restrict__ dhi, u16* __restrict__ dlo,
                        int K0, int KPd, int H, size_t sbatch, size_t dbatch) {
    __shared__ float tile[32][33];
    int bz = blockIdx.z;
    src += (size_t)bz * sbatch;
    size_t dob = (size_t)bz * dbatch;
    int k0 = blockIdx.x * 32, h0 = blockIdx.y * 32;
    int tx = threadIdx.x, ty = threadIdx.y;
    for (int i = ty; i < 32; i += 8) {
        int k = k0 + i;
        tile[i][tx] = (k < K0) ? src[(size_t)k * H + (h0 + tx)] : 0.f;
    }
    __syncthreads();
    for (int i = ty; i < 32; i += 8) {
        int h = h0 + i, k = k0 + tx;
        float v = tile[tx][i];
        u16 hv = f2bf(v);
        dhi[dob + (size_t)h * KPd + k] = hv;
        if (dlo) dlo[dob + (size_t)h * KPd + k] = f2bf(v - bf2f(hv));
    }
}

// ---- build fusion input x (9 LayerNorms + mask), emit bf16 hi/lo split ----
__global__ __launch_bounds__(512)
void build_x(const float* __restrict__ z1, const float* __restrict__ z2, const float* __restrict__ z3,
             const float* __restrict__ mask,
             const float* __restrict__ ln_g, const float* __restrict__ ln_b,
             const float* __restrict__ lnp_g, const float* __restrict__ lnp_b,
             u16* __restrict__ xhi, u16* __restrict__ xlo) {
    __shared__ float red[18];
    int n = blockIdx.x, d = threadIdx.x;
    float a = z1[(size_t)n * DMODEL + d];
    float b = z2[(size_t)n * DMODEL + d];
    float c = z3[(size_t)n * DMODEL + d];
    float gg = ln_g[d], bb = ln_b[d], pg = lnp_g[d], pb = lnp_b[d];
    size_t base = (size_t)n * KP;

    auto emit = [&](int seg, float v) {
        u16 h = f2bf(v);
        xhi[base + seg * DMODEL + d] = h;
        xlo[base + seg * DMODEL + d] = f2bf(v - bf2f(h));
    };
    float2 s;
    s = bstats512(a, d, red); float z1n = (a - s.x) * s.y * gg + bb;
    s = bstats512(b, d, red); float z2n = (b - s.x) * s.y * gg + bb;
    s = bstats512(c, d, red); float z3n = (c - s.x) * s.y * gg + bb;
    emit(0, z1n); emit(1, z2n); emit(2, z3n);
    auto pln = [&](int seg, float v) {
        float2 st = bstats512(v, d, red);
        emit(seg, (v - st.x) * st.y * pg + pb);
    };
    pln(3, z1n - z2n); pln(4, z1n - z3n); pln(5, z2n - z3n);
    pln(6, z1n * z2n); pln(7, z1n * z3n); pln(8, z2n * z3n);
    if (d < 64) {   // mask cols 4608..4610 + zero pad 4611..4671
        int col = 9 * DMODEL + d;
        float v = (d < 3) ? mask[(size_t)n * 3 + d] : 0.f;
        u16 h = f2bf(v);
        xhi[base + col] = h;
        xlo[base + col] = f2bf(v - bf2f(h));
    }
}

// ================= 128x256 (BMxBN) bf16 MFMA GEMM, BK=64, 512 threads =================
// LDS rows are 64 elems = 128 B = one cache line. XOR swizzle: LDS chunk c holds global
// chunk c ^ (row&7); staging picks global chunk ((lane&7)^(lane>>3 &7)), fragment reads
// chunk (q ^ (fr&7)). Wave grid: wm=(w&1)*64, wn=(w>>1)*64; per-wave 64x64, acc[4][4].
// A/B-frag: [r=lane&15][k=(lane>>4)*8+j]; C/D: row=(lane>>4)*4+reg, col=lane&15.

#define GEMM_DEFS                                                             \
    int t = threadIdx.x;                                                      \
    int lane = t & 63, w = t >> 6;                                            \
    int r8 = lane >> 3;                                                       \
    int ce = ((lane & 7) ^ r8) * 8;       /* swizzled global chunk, elems */  \
    int fr = lane & 15, q4 = lane >> 4;                                       \
    int wm = (w & 1) * 64, wn = (w >> 1) * 64;                                \
    f32x4 acc[4][4];                                                          \
    { f32x4 z4 = {0.f, 0.f, 0.f, 0.f};                                        \
      _Pragma("unroll") for (int i = 0; i < 4; i++)                           \
      _Pragma("unroll") for (int j = 0; j < 4; j++) acc[i][j] = z4; }         \
    u16* lA0 = lA + (w * 16) * BK;                                            \
    u16* lA1 = lA + (w * 16 + 8) * BK;                                        \
    u16* lB0 = lB + (w * 32) * BK;                                            \
    u16* lB1 = lB + (w * 32 + 8) * BK;                                        \
    u16* lB2 = lB + (w * 32 + 16) * BK;                                       \
    u16* lB3 = lB + (w * 32 + 24) * BK;

#define GEMM_KSTEP                                                            \
        __syncthreads();                                                      \
        async_cp16(gA0, lA0); async_cp16(gA1, lA1);                           \
        async_cp16(gB0, lB0); async_cp16(gB1, lB1);                           \
        async_cp16(gB2, lB2); async_cp16(gB3, lB3);                           \
        gA0 += BK; gA1 += BK; gB0 += BK; gB1 += BK; gB2 += BK; gB3 += BK;     \
        __syncthreads();                                                      \
        _Pragma("unroll") for (int ks = 0; ks < 2; ks++) {                    \
            bf16x8 af[4], bfr[4];                                             \
            int cofs = (((q4 + ks * 4) ^ (fr & 7)) * 8);                      \
            _Pragma("unroll") for (int i = 0; i < 4; i++)                     \
                af[i] = *(const bf16x8*)&lA[(wm + i * 16 + fr) * BK + cofs];  \
            _Pragma("unroll") for (int j = 0; j < 4; j++)                     \
                bfr[j] = *(const bf16x8*)&lB[(wn + j * 16 + fr) * BK + cofs]; \
            _Pragma("unroll") for (int i = 0; i < 4; i++)                     \
            _Pragma("unroll") for (int j = 0; j < 4; j++)                     \
                acc[i][j] = __builtin_amdgcn_mfma_f32_16x16x32_bf16(af[i], bfr[j], acc[i][j], 0, 0, 0); \
        }

// ---- router fc1: partial GEMM; 1D grid 384: part = b>>6 (region*2+khalf), mt = b&63 ----
__global__ __launch_bounds__(512, 4)
void router_fc1(const u16* __restrict__ xhi, const u16* __restrict__ xlo,
                const u16* __restrict__ rw1hi, const u16* __restrict__ rw1lo,
                float* __restrict__ rpart) {
    int part = blockIdx.x >> 6, mt = blockIdx.x & 63;
    int region = part >> 1, half = part & 1;
    const u16* A = (region == 2) ? xlo : xhi;        // hh: hi*hi, hl: hi*lo, lh: lo*hi
    const u16* B = (region == 1) ? rw1lo : rw1hi;
    int kbase = half ? 2304 : 0;
    int klen  = half ? 2368 : 2304;                  // both divisible by 64

    __shared__ u16 lA[128 * BK];
    __shared__ u16 lB[256 * BK];
    GEMM_DEFS

    const u16* gA0 = A + (size_t)(mt * 128 + w * 16 + r8) * KP + kbase + ce;
    const u16* gA1 = A + (size_t)(mt * 128 + w * 16 + 8 + r8) * KP + kbase + ce;
    const u16* gB0 = B + (size_t)(w * 32 + r8) * KP + kbase + ce;
    const u16* gB1 = B + (size_t)(w * 32 + 8 + r8) * KP + kbase + ce;
    const u16* gB2 = B + (size_t)(w * 32 + 16 + r8) * KP + kbase + ce;
    const u16* gB3 = B + (size_t)(w * 32 + 24 + r8) * KP + kbase + ce;

    for (int k0 = 0; k0 < klen; k0 += BK) {
        GEMM_KSTEP
    }
    float* outp = rpart + (size_t)part * ((size_t)N_TOK * RHDIM);
    int cn = lane & 15;
    #pragma unroll
    for (int i = 0; i < 4; i++)
        #pragma unroll
        for (int rr = 0; rr < 4; rr++) {
            int mg = mt * 128 + wm + i * 16 + q4 * 4 + rr;
            #pragma unroll
            for (int j = 0; j < 4; j++)
                outp[(size_t)mg * RHDIM + wn + j * 16 + cn] = acc[i][j][rr];
        }
}

__global__ void router_act(const float* __restrict__ rpart, const float* __restrict__ r_b1,
                           float* __restrict__ rh) {
    int idx = blockIdx.x * 256 + threadIdx.x;
    float v = 0.f;
    #pragma unroll
    for (int p = 0; p < 6; p++) v += rpart[(size_t)p * ((size_t)N_TOK * RHDIM) + idx];
    v += r_b1[idx & (RHDIM - 1)];
    rh[idx] = gelu_exact(v);
}

// ---- logits + top-2 + gates + expert scatter: one wave per token ----
__global__ __launch_bounds__(256)
void logits_topk(const float* __restrict__ rh, const float* __restrict__ r_w2,
                 const float* __restrict__ r_b2, const float* __restrict__ log_temp,
                 float* __restrict__ pgate, int* __restrict__ pexp,
                 int* __restrict__ lists, int* __restrict__ counts) {
    int t = threadIdx.x, wave = t >> 6, lane = t & 63;
    int n = blockIdx.x * 4 + wave;
    int e = lane & 7, ch = lane >> 3;
    const float* r = rh + (size_t)n * RHDIM;
    float s = 0.f;
    #pragma unroll
    for (int k = 0; k < 32; k++) s += r[ch * 32 + k] * r_w2[(ch * 32 + k) * 8 + e];
    s += __shfl_xor(s, 8);
    s += __shfl_xor(s, 16);
    s += __shfl_xor(s, 32);
    float temp = fminf(fmaxf(expf(log_temp[0]), 1e-3f), 100.f);
    float logit = (s + r_b2[e]) / temp;
    float l[8];
    #pragma unroll
    for (int i = 0; i < 8; i++) l[i] = __shfl(logit, i);
    if (lane == 0) {
        int i1 = 0;
        #pragma unroll
        for (int i = 1; i < 8; i++) if (l[i] > l[i1]) i1 = i;   // first-occurrence max (matches top_k)
        int i2 = (i1 == 0) ? 1 : 0;
        #pragma unroll
        for (int i = 0; i < 8; i++) if (i != i1 && l[i] > l[i2]) i2 = i;
        float p = expf(l[i2] - l[i1]);
        float g1 = 1.f / (1.f + p);
        float g2 = p / (1.f + p);
        pgate[n * 2] = g1;     pexp[n * 2] = i1;
        pgate[n * 2 + 1] = g2; pexp[n * 2 + 1] = i2;
        int pos1 = atomicAdd(&counts[i1], 1);
        lists[(size_t)i1 * N_TOK + pos1] = n * 2;
        int pos2 = atomicAdd(&counts[i2], 1);
        lists[(size_t)i2 * N_TOK + pos2] = n * 2 + 1;
    }
}

// ---- tile scheduler: counts -> compact (e,mt) list, round-robin over experts ----
__global__ void sched_tiles(const int* __restrict__ counts, int* __restrict__ tiles) {
    if (threadIdx.x == 0) {
        int rem[NEXP], t = 0;
        for (int e = 0; e < NEXP; e++) rem[e] = (counts[e] + 127) >> 7;
        for (int mt = 0; mt < MAXT; mt++)
            for (int e = 0; e < NEXP; e++)
                if (mt < rem[e]) tiles[t++] = (e << 16) | mt;
        for (; t < MAXT; t++) tiles[t] = -1;   // sentinel
    }
}

// ---- expert fc1: gathered [cnt,KP] x [KP,1024] bf16 GEMM, gelu -> eh bf16 ----
// 1D grid MAXT*4: ti = b % MAXT (consecutive blocks = different experts), nt = b / MAXT
__global__ __launch_bounds__(512, 4)
void expert_fc1(const u16* __restrict__ xhi, const u16* __restrict__ w1t,
                const float* __restrict__ e_b1, const int* __restrict__ lists,
                const int* __restrict__ counts, const int* __restrict__ tiles,
                u16* __restrict__ eh) {
    int ti = blockIdx.x % MAXT, nt = blockIdx.x / MAXT;
    int info = tiles[ti];
    if (info < 0) return;
    int e = info >> 16, mt = info & 0xFFFF;
    int cnt = counts[e];

    __shared__ u16 lA[128 * BK];
    __shared__ u16 lB[256 * BK];
    __shared__ int rows[128];
    int tt = threadIdx.x;
    if (tt < 128) {
        int m = mt * 128 + tt;
        rows[tt] = lists[(size_t)e * N_TOK + (m < cnt ? m : 0)];   // clamp tail to valid entry
    }
    __syncthreads();

    GEMM_DEFS

    const u16* gA0 = xhi + (size_t)(rows[w * 16 + r8] >> 1) * KP + ce;
    const u16* gA1 = xhi + (size_t)(rows[w * 16 + 8 + r8] >> 1) * KP + ce;
    const u16* wb = w1t + (size_t)e * HEXP * KP + (size_t)(nt * 256) * KP;
    const u16* gB0 = wb + (size_t)(w * 32 + r8) * KP + ce;
    const u16* gB1 = wb + (size_t)(w * 32 + 8 + r8) * KP + ce;
    const u16* gB2 = wb + (size_t)(w * 32 + 16 + r8) * KP + ce;
    const u16* gB3 = wb + (size_t)(w * 32 + 24 + r8) * KP + ce;

    for (int k0 = 0; k0 < KP; k0 += BK) {
        GEMM_KSTEP
    }
    int cn = lane & 15;
    #pragma unroll
    for (int i = 0; i < 4; i++)
        #pragma unroll
        for (int rr = 0; rr < 4; rr++) {
            int ml = wm + i * 16 + q4 * 4 + rr;
            int mg = mt * 128 + ml;
            if (mg < cnt) {
                int entry = rows[ml];
                #pragma unroll
                for (int j = 0; j < 4; j++) {
                    int col = nt * 256 + wn + j * 16 + cn;
                    float v = acc[i][j][rr] + e_b1[(size_t)e * HEXP + col];
                    eh[(size_t)entry * HEXP + col] = f2bf(gelu_exact(v));
                }
            }
        }
}

// ---- expert fc2: gathered [cnt,1024] x [1024,512] bf16 GEMM -> per-slot fp32 outs ----
__global__ __launch_bounds__(512, 4)
void expert_fc2(const u16* __restrict__ eh, const u16* __restrict__ w2t,
                const int* __restrict__ lists, const int* __restrict__ counts,
                const int* __restrict__ tiles, float* __restrict__ outs) {
    int ti = blockIdx.x % MAXT, nt = blockIdx.x / MAXT;
    int info = tiles[ti];
    if (info < 0) return;
    int e = info >> 16, mt = info & 0xFFFF;
    int cnt = counts[e];

    __shared__ u16 lA[128 * BK];
    __shared__ u16 lB[256 * BK];
    __shared__ int rows[128];
    int tt = threadIdx.x;
    if (tt < 128) {
        int m = mt * 128 + tt;
        rows[tt] = lists[(size_t)e * N_TOK + (m < cnt ? m : 0)];
    }
    __syncthreads();

    GEMM_DEFS

    const u16* gA0 = eh + (size_t)rows[w * 16 + r8] * HEXP + ce;
    const u16* gA1 = eh + (size_t)rows[w * 16 + 8 + r8] * HEXP + ce;
    const u16* wb = w2t + (size_t)e * DMODEL * HEXP + (size_t)(nt * 256) * HEXP;
    const u16* gB0 = wb + (size_t)(w * 32 + r8) * HEXP + ce;
    const u16* gB1 = wb + (size_t)(w * 32 + 8 + r8) * HEXP + ce;
    const u16* gB2 = wb + (size_t)(w * 32 + 16 + r8) * HEXP + ce;
    const u16* gB3 = wb + (size_t)(w * 32 + 24 + r8) * HEXP + ce;

    for (int k0 = 0; k0 < HEXP; k0 += BK) {
        GEMM_KSTEP
    }
    int cn = lane & 15;
    #pragma unroll
    for (int i = 0; i < 4; i++)
        #pragma unroll
        for (int rr = 0; rr < 4; rr++) {
            int ml = wm + i * 16 + q4 * 4 + rr;
            int mg = mt * 128 + ml;
            if (mg < cnt) {
                int entry = rows[ml];
                #pragma unroll
                for (int j = 0; j < 4; j++) {
                    int col = nt * 256 + wn + j * 16 + cn;
                    outs[(size_t)entry * DMODEL + col] = acc[i][j][rr];
                }
            }
        }
}

// ---- combine: gate*(outs+b2) + masked residual + final LN ----
__global__ __launch_bounds__(512)
void combine_ln(const float* __restrict__ outs, const float* __restrict__ pgate,
                const int* __restrict__ pexp, const float* __restrict__ e_b2,
                const float* __restrict__ mask, const u16* __restrict__ xhi,
                const u16* __restrict__ xlo, const float* __restrict__ oln_g,
                const float* __restrict__ oln_b, float* __restrict__ out) {
    __shared__ float red[18];
    int n = blockIdx.x, d = threadIdx.x;
    float g0 = pgate[n * 2], g1 = pgate[n * 2 + 1];
    int e0 = pexp[n * 2], e1 = pexp[n * 2 + 1];
    float o = g0 * (outs[(size_t)(n * 2) * DMODEL + d] + e_b2[(size_t)e0 * DMODEL + d])
            + g1 * (outs[(size_t)(n * 2 + 1) * DMODEL + d] + e_b2[(size_t)e1 * DMODEL + d]);
    float m0 = mask[n * 3 + 0], m1 = mask[n * 3 + 1], m2 = mask[n * 3 + 2];
    float denom = fmaxf(m0 + m1 + m2, 1.f);
    size_t xb = (size_t)n * KP;
    float z1n = bf2f(xhi[xb + d]) + bf2f(xlo[xb + d]);                       // hi+lo = fp32-exact
    float z2n = bf2f(xhi[xb + DMODEL + d]) + bf2f(xlo[xb + DMODEL + d]);
    float z3n = bf2f(xhi[xb + 2 * DMODEL + d]) + bf2f(xlo[xb + 2 * DMODEL + d]);
    float z = o + (m0 * z1n + m1 * z2n + m2 * z3n) / denom;
    float2 st = bstats512(z, d, red);
    out[(size_t)n * DMODEL + d] = (z - st.x) * st.y * oln_g[d] + oln_b[d];
}

extern "C" void kernel_launch(void* const* d_in, const int* in_sizes, int n_in,
                              void* d_out, int out_size, void* d_ws, size_t ws_size,
                              hipStream_t stream) {
    (void)in_sizes; (void)n_in; (void)out_size; (void)ws_size;
    const float* z1       = (const float*)d_in[0];
    const float* z2       = (const float*)d_in[1];
    const float* z3       = (const float*)d_in[2];
    const float* mask     = (const float*)d_in[3];
    const float* ln_g     = (const float*)d_in[4];
    const float* ln_b     = (const float*)d_in[5];
    const float* lnp_g    = (const float*)d_in[6];
    const float* lnp_b    = (const float*)d_in[7];
    const float* oln_g    = (const float*)d_in[8];
    const float* oln_b    = (const float*)d_in[9];
    const float* r_w1     = (const float*)d_in[10];
    const float* r_b1     = (const float*)d_in[11];
    const float* r_w2     = (const float*)d_in[12];
    const float* r_b2     = (const float*)d_in[13];
    const float* log_temp = (const float*)d_in[14];
    const float* e_w1     = (const float*)d_in[15];
    const float* e_b1     = (const float*)d_in[16];
    const float* e_w2     = (const float*)d_in[17];
    const float* e_b2     = (const float*)d_in[18];
    float* out = (float*)d_out;

    char* p = (char*)d_ws;
    auto carve = [&](size_t bytes) { char* r = p; p += (bytes + 255) & ~(size_t)255; return r; };
    u16*   xhi    = (u16*)carve((size_t)N_TOK * KP * 2);
    u16*   xlo    = (u16*)carve((size_t)N_TOK * KP * 2);
    u16*   w1t    = (u16*)carve((size_t)NEXP * HEXP * KP * 2);
    u16*   w2t    = (u16*)carve((size_t)NEXP * DMODEL * HEXP * 2);
    u16*   rw1hi  = (u16*)carve((size_t)RHDIM * KP * 2);
    u16*   rw1lo  = (u16*)carve((size_t)RHDIM * KP * 2);
    float* rpart  = (float*)carve((size_t)6 * N_TOK * RHDIM * 4);
    float* rh     = (float*)carve((size_t)N_TOK * RHDIM * 4);
    u16*   eh     = (u16*)carve((size_t)NPAIR * HEXP * 2);
    float* outsb  = (float*)carve((size_t)NPAIR * DMODEL * 4);
    float* pgate  = (float*)carve((size_t)NPAIR * 4);
    int*   pexp   = (int*)carve((size_t)NPAIR * 4);
    int*   lists  = (int*)carve((size_t)NEXP * N_TOK * 4);
    int*   counts = (int*)carve(256);
    int*   tiles  = (int*)carve(MAXT * 4);

    dim3 tb(32, 8);
    transpose_f32_bf16<<<dim3(KP / 32, HEXP / 32, NEXP), tb, 0, stream>>>(
        e_w1, w1t, (u16*)nullptr, IN_REAL, KP, HEXP, (size_t)IN_REAL * HEXP, (size_t)HEXP * KP);
    transpose_f32_bf16<<<dim3(HEXP / 32, DMODEL / 32, NEXP), tb, 0, stream>>>(
        e_w2, w2t, (u16*)nullptr, HEXP, HEXP, DMODEL, (size_t)HEXP * DMODEL, (size_t)DMODEL * HEXP);
    transpose_f32_bf16<<<dim3(KP / 32, RHDIM / 32, 1), tb, 0, stream>>>(
        r_w1, rw1hi, rw1lo, IN_REAL, KP, RHDIM, (size_t)0, (size_t)0);

    build_x<<<N_TOK, 512, 0, stream>>>(z1, z2, z3, mask, ln_g, ln_b, lnp_g, lnp_b, xhi, xlo);

    router_fc1<<<384, 512, 0, stream>>>(xhi, xlo, rw1hi, rw1lo, rpart);
    router_act<<<(N_TOK * RHDIM) / 256, 256, 0, stream>>>(rpart, r_b1, rh);

    hipMemsetAsync(counts, 0, 256, stream);
    logits_topk<<<N_TOK / 4, 256, 0, stream>>>(rh, r_w2, r_b2, log_temp, pgate, pexp, lists, counts);
    sched_tiles<<<1, 64, 0, stream>>>(counts, tiles);

    expert_fc1<<<MAXT * 4, 512, 0, stream>>>(xhi, w1t, e_b1, lists, counts, tiles, eh);
    expert_fc2<<<MAXT * 2, 512, 0, stream>>>(eh, w2t, lists, counts, tiles, outsb);

    combine_ln<<<N_TOK, 512, 0, stream>>>(outsb, pgate, pexp, e_b2, mask, xhi, xlo, oln_g, oln_b, out);
}

// Round 5
// 1009.342 us; speedup vs baseline: 1.3341x; 1.0331x over previous
//
#include <hip/hip_runtime.h>
#include <math.h>

#define N_TOK 8192
#define DMODEL 512
#define NEXP 8
#define HEXP 1024
#define RHDIM 256
#define KP 4672          // IN_DIM=4611 padded to multiple of 64 (zero-filled)
#define IN_REAL 4611
#define BK 64            // K-tile; one LDS row = 128 B = one cache line
#define NPAIR (N_TOK * 2)
#define MAXT 136         // max expert tiles

typedef unsigned short u16;
typedef __bf16 bf16x8 __attribute__((ext_vector_type(8)));
typedef float f32x4 __attribute__((ext_vector_type(4)));

__device__ inline u16 f2bf(float f) {
    union { float f; unsigned u; } x; x.f = f;
    unsigned r = x.u + 0x7FFFu + ((x.u >> 16) & 1u);   // round-to-nearest-even
    return (u16)(r >> 16);
}
__device__ inline float bf2f(u16 u) {
    union { unsigned u; float f; } x; x.u = ((unsigned)u) << 16;
    return x.f;
}
__device__ inline float gelu_exact(float v) {
    return 0.5f * v * (1.f + erff(v * 0.70710678118654752440f));
}

// async global->LDS, 16B per lane; lds base wave-uniform, lane lands at base + lane*16
__device__ inline void async_cp16(const u16* g, u16* l) {
    __builtin_amdgcn_global_load_lds(
        (const __attribute__((address_space(1))) unsigned int*)g,
        (__attribute__((address_space(3))) unsigned int*)l, 16, 0, 0);
}

// ---- multi-stat block reduction for 512-thread blocks: v[i] -> block sum ----
template<int M>
__device__ inline void breduce(float (&v)[M], int tid, float* red) {
    #pragma unroll
    for (int o = 32; o > 0; o >>= 1)
        #pragma unroll
        for (int i = 0; i < M; i++) v[i] += __shfl_xor(v[i], o);
    __syncthreads();                        // guard red[] reuse
    if ((tid & 63) == 0) {
        #pragma unroll
        for (int i = 0; i < M; i++) red[(tid >> 6) * M + i] = v[i];
    }
    __syncthreads();
    if (tid < M) {
        float S = 0.f;
        #pragma unroll
        for (int w8 = 0; w8 < 8; w8++) S += red[w8 * M + tid];
        red[96 + tid] = S;
    }
    __syncthreads();
    #pragma unroll
    for (int i = 0; i < M; i++) v[i] = red[96 + i];
}

// ---- block stats for 512-thread blocks: returns (mean, rsqrt(var+eps)) ----
__device__ inline float2 bstats512(float v, int tid, float* red) {
    float s = v, q = v * v;
    #pragma unroll
    for (int o = 32; o > 0; o >>= 1) {
        s += __shfl_xor(s, o);
        q += __shfl_xor(q, o);
    }
    __syncthreads();
    if ((tid & 63) == 0) { red[(tid >> 6) * 2] = s; red[(tid >> 6) * 2 + 1] = q; }
    __syncthreads();
    if (tid == 0) {
        float S = 0.f, Q = 0.f;
        #pragma unroll
        for (int i = 0; i < 8; i++) { S += red[i * 2]; Q += red[i * 2 + 1]; }
        float m = S * (1.f / 512.f);
        float var = fmaxf(Q * (1.f / 512.f) - m * m, 0.f);
        red[16] = m;
        red[17] = rsqrtf(var + 1e-5f);
    }
    __syncthreads();
    return make_float2(red[16], red[17]);
}

// ---- transpose fp32 [K0,H] -> bf16 [H,KPd] (zero-fill k>=K0), optional hi/lo split ----
__global__ __launch_bounds__(256)
void transpose_f32_bf16(const float* __restrict__ src, u16* __restrict__ dhi, u16* __restrict__ dlo,
                        int K0, int KPd, int H, size_t sbatch, size_t dbatch) {
    __shared__ float tile[32][33];
    int bz = blockIdx.z;
    src += (size_t)bz * sbatch;
    size_t dob = (size_t)bz * dbatch;
    int k0 = blockIdx.x * 32, h0 = blockIdx.y * 32;
    int tx = threadIdx.x, ty = threadIdx.y;
    for (int i = ty; i < 32; i += 8) {
        int k = k0 + i;
        tile[i][tx] = (k < K0) ? src[(size_t)k * H + (h0 + tx)] : 0.f;
    }
    __syncthreads();
    for (int i = ty; i < 32; i += 8) {
        int h = h0 + i, k = k0 + tx;
        float v = tile[tx][i];
        u16 hv = f2bf(v);
        dhi[dob + (size_t)h * KPd + k] = hv;
        if (dlo) dlo[dob + (size_t)h * KPd + k] = f2bf(v - bf2f(hv));
    }
}

// ---- build fusion input x (9 LayerNorms + mask), emit bf16 hi/lo split ----
__global__ __launch_bounds__(512)
void build_x(const float* __restrict__ z1, const float* __restrict__ z2, const float* __restrict__ z3,
             const float* __restrict__ mask,
             const float* __restrict__ ln_g, const float* __restrict__ ln_b,
             const float* __restrict__ lnp_g, const float* __restrict__ lnp_b,
             u16* __restrict__ xhi, u16* __restrict__ xlo) {
    __shared__ float red[108];
    int n = blockIdx.x, d = threadIdx.x;
    float a = z1[(size_t)n * DMODEL + d];
    float b = z2[(size_t)n * DMODEL + d];
    float c = z3[(size_t)n * DMODEL + d];
    float gg = ln_g[d], bb = ln_b[d], pg = lnp_g[d], pb = lnp_b[d];
    size_t base = (size_t)n * KP;

    auto emit = [&](int seg, float v) {
        u16 h = f2bf(v);
        xhi[base + seg * DMODEL + d] = h;
        xlo[base + seg * DMODEL + d] = f2bf(v - bf2f(h));
    };
    auto lnv = [](float v, float s, float q, float g, float bo) {
        float m = s * (1.f / 512.f);
        float var = fmaxf(q * (1.f / 512.f) - m * m, 0.f);
        return (v - m) * rsqrtf(var + 1e-5f) * g + bo;
    };
    // phase 1: three base LNs in one reduction round
    float v6[6] = {a, a * a, b, b * b, c, c * c};
    breduce<6>(v6, d, red);
    float z1n = lnv(a, v6[0], v6[1], gg, bb);
    float z2n = lnv(b, v6[2], v6[3], gg, bb);
    float z3n = lnv(c, v6[4], v6[5], gg, bb);
    emit(0, z1n); emit(1, z2n); emit(2, z3n);
    // phase 2: six pair LNs in one reduction round
    float d12 = z1n - z2n, d13 = z1n - z3n, d23 = z2n - z3n;
    float p12 = z1n * z2n, p13 = z1n * z3n, p23 = z2n * z3n;
    float v12[12] = {d12, d12 * d12, d13, d13 * d13, d23, d23 * d23,
                     p12, p12 * p12, p13, p13 * p13, p23, p23 * p23};
    breduce<12>(v12, d, red);
    emit(3, lnv(d12, v12[0], v12[1], pg, pb));
    emit(4, lnv(d13, v12[2], v12[3], pg, pb));
    emit(5, lnv(d23, v12[4], v12[5], pg, pb));
    emit(6, lnv(p12, v12[6], v12[7], pg, pb));
    emit(7, lnv(p13, v12[8], v12[9], pg, pb));
    emit(8, lnv(p23, v12[10], v12[11], pg, pb));
    if (d < 64) {   // mask cols 4608..4610 + zero pad 4611..4671
        int col = 9 * DMODEL + d;
        float v = (d < 3) ? mask[(size_t)n * 3 + d] : 0.f;
        u16 h = f2bf(v);
        xhi[base + col] = h;
        xlo[base + col] = f2bf(v - bf2f(h));
    }
}

// ================= 128x128 bf16 MFMA GEMM, BK=64, 256 threads (4 waves) =================
// LDS rows 64 elems = 128 B = one cache line. XOR swizzle: LDS chunk c holds global chunk
// c ^ (row&7). Staging: wave w stages rows [w*32, w*32+32), 4 cp16 each for A and B;
// lane l -> row +8i+(l>>3), global chunk ((l&7)^(l>>3)). Fragment read chunk (q ^ (fr&7)).
// Waves 2x2: wm=(w&1)*64, wn=(w>>1)*64; per-wave 64x64, acc[4][4].
// A/B-frag: [r=lane&15][k=(lane>>4)*8+j]; C/D: row=(lane>>4)*4+reg, col=lane&15.

#define GEMM_DEFS                                                             \
    int t = threadIdx.x;                                                      \
    int lane = t & 63, w = t >> 6;                                            \
    int r8 = lane >> 3;                                                       \
    int ce = ((lane & 7) ^ r8) * 8;       /* swizzled global chunk, elems */  \
    int fr = lane & 15, q4 = lane >> 4;                                       \
    int wm = (w & 1) * 64, wn = (w >> 1) * 64;                                \
    f32x4 acc[4][4];                                                          \
    { f32x4 z4 = {0.f, 0.f, 0.f, 0.f};                                        \
      _Pragma("unroll") for (int i = 0; i < 4; i++)                           \
      _Pragma("unroll") for (int j = 0; j < 4; j++) acc[i][j] = z4; }         \
    u16 *lAp[4], *lBp[4];                                                     \
    _Pragma("unroll") for (int i = 0; i < 4; i++) {                           \
        lAp[i] = lA + (w * 32 + 8 * i) * BK;                                  \
        lBp[i] = lB + (w * 32 + 8 * i) * BK;                                  \
    }

#define GEMM_KSTEP                                                            \
        __syncthreads();                                                      \
        _Pragma("unroll") for (int i = 0; i < 4; i++) {                       \
            async_cp16(gA[i], lAp[i]); async_cp16(gB[i], lBp[i]);             \
            gA[i] += BK; gB[i] += BK;                                         \
        }                                                                     \
        __syncthreads();                                                      \
        _Pragma("unroll") for (int ks = 0; ks < 2; ks++) {                    \
            bf16x8 af[4], bfr[4];                                             \
            int cofs = (((q4 + ks * 4) ^ (fr & 7)) * 8);                      \
            _Pragma("unroll") for (int i = 0; i < 4; i++)                     \
                af[i] = *(const bf16x8*)&lA[(wm + i * 16 + fr) * BK + cofs];  \
            _Pragma("unroll") for (int j = 0; j < 4; j++)                     \
                bfr[j] = *(const bf16x8*)&lB[(wn + j * 16 + fr) * BK + cofs]; \
            _Pragma("unroll") for (int i = 0; i < 4; i++)                     \
            _Pragma("unroll") for (int j = 0; j < 4; j++)                     \
                acc[i][j] = __builtin_amdgcn_mfma_f32_16x16x32_bf16(af[i], bfr[j], acc[i][j], 0, 0, 0); \
        }

// ---- router fc1: partial GEMM; 1D grid 768: nt = b&1, mt = (b>>1)&63, part = b>>7 ----
__global__ __launch_bounds__(256, 4)
void router_fc1(const u16* __restrict__ xhi, const u16* __restrict__ xlo,
                const u16* __restrict__ rw1hi, const u16* __restrict__ rw1lo,
                float* __restrict__ rpart) {
    int nt = blockIdx.x & 1, mt = (blockIdx.x >> 1) & 63, part = blockIdx.x >> 7;
    int region = part >> 1, half = part & 1;
    const u16* A = (region == 2) ? xlo : xhi;        // hh: hi*hi, hl: hi*lo, lh: lo*hi
    const u16* B = (region == 1) ? rw1lo : rw1hi;
    int kbase = half ? 2304 : 0;
    int klen  = half ? 2368 : 2304;                  // both divisible by 64

    __shared__ u16 lA[128 * BK];
    __shared__ u16 lB[128 * BK];
    GEMM_DEFS

    const u16* gA[4]; const u16* gB[4];
    #pragma unroll
    for (int i = 0; i < 4; i++) {
        gA[i] = A + (size_t)(mt * 128 + w * 32 + 8 * i + r8) * KP + kbase + ce;
        gB[i] = B + (size_t)(nt * 128 + w * 32 + 8 * i + r8) * KP + kbase + ce;
    }

    for (int k0 = 0; k0 < klen; k0 += BK) {
        GEMM_KSTEP
    }
    float* outp = rpart + (size_t)part * ((size_t)N_TOK * RHDIM);
    int cn = lane & 15;
    #pragma unroll
    for (int i = 0; i < 4; i++)
        #pragma unroll
        for (int rr = 0; rr < 4; rr++) {
            int mg = mt * 128 + wm + i * 16 + q4 * 4 + rr;
            #pragma unroll
            for (int j = 0; j < 4; j++)
                outp[(size_t)mg * RHDIM + nt * 128 + wn + j * 16 + cn] = acc[i][j][rr];
        }
}

// ---- fused: partial-sum + bias + gelu + logits + top-2 + gates + scatter (1 wave/token) ----
__global__ __launch_bounds__(256)
void logits_topk(const float* __restrict__ rpart, const float* __restrict__ r_b1,
                 const float* __restrict__ r_w2, const float* __restrict__ r_b2,
                 const float* __restrict__ log_temp,
                 float* __restrict__ pgate, int* __restrict__ pexp,
                 int* __restrict__ lists, int* __restrict__ counts) {
    int t = threadIdx.x, wave = t >> 6, lane = t & 63;
    int n = blockIdx.x * 4 + wave;
    // each lane owns rh cols lane*4..lane*4+3
    float4 v = {0.f, 0.f, 0.f, 0.f};
    #pragma unroll
    for (int p = 0; p < 6; p++) {
        float4 s = ((const float4*)(rpart + (size_t)p * ((size_t)N_TOK * RHDIM) + (size_t)n * RHDIM))[lane];
        v.x += s.x; v.y += s.y; v.z += s.z; v.w += s.w;
    }
    float4 b1 = ((const float4*)r_b1)[lane];
    float rh0 = gelu_exact(v.x + b1.x);
    float rh1 = gelu_exact(v.y + b1.y);
    float rh2 = gelu_exact(v.z + b1.z);
    float rh3 = gelu_exact(v.w + b1.w);
    int k = lane * 4;
    float p8[8];
    #pragma unroll
    for (int e = 0; e < 8; e++)
        p8[e] = rh0 * r_w2[(k + 0) * 8 + e] + rh1 * r_w2[(k + 1) * 8 + e]
              + rh2 * r_w2[(k + 2) * 8 + e] + rh3 * r_w2[(k + 3) * 8 + e];
    #pragma unroll
    for (int o = 32; o > 0; o >>= 1)
        #pragma unroll
        for (int e = 0; e < 8; e++) p8[e] += __shfl_xor(p8[e], o);
    if (lane == 0) {
        float temp = fminf(fmaxf(expf(log_temp[0]), 1e-3f), 100.f);
        float l[8];
        #pragma unroll
        for (int e = 0; e < 8; e++) l[e] = (p8[e] + r_b2[e]) / temp;
        int i1 = 0;
        #pragma unroll
        for (int i = 1; i < 8; i++) if (l[i] > l[i1]) i1 = i;   // first-occurrence max (matches top_k)
        int i2 = (i1 == 0) ? 1 : 0;
        #pragma unroll
        for (int i = 0; i < 8; i++) if (i != i1 && l[i] > l[i2]) i2 = i;
        float p = expf(l[i2] - l[i1]);
        float g1 = 1.f / (1.f + p);
        float g2 = p / (1.f + p);
        pgate[n * 2] = g1;     pexp[n * 2] = i1;
        pgate[n * 2 + 1] = g2; pexp[n * 2 + 1] = i2;
        int pos1 = atomicAdd(&counts[i1], 1);
        lists[(size_t)i1 * N_TOK + pos1] = n * 2;
        int pos2 = atomicAdd(&counts[i2], 1);
        lists[(size_t)i2 * N_TOK + pos2] = n * 2 + 1;
    }
}

// ---- tile scheduler: counts -> compact (e,mt) list, expert-major ----
// expert-major + nt-in-low-bits grid => same-XCD neighbors share expert B-slice (L2 reuse)
__global__ void sched_tiles(const int* __restrict__ counts, int* __restrict__ tiles) {
    if (threadIdx.x == 0) {
        int tcount = 0;
        for (int e = 0; e < NEXP; e++) {
            int nt = (counts[e] + 127) >> 7;
            for (int mt = 0; mt < nt; mt++) tiles[tcount++] = (e << 16) | mt;
        }
        for (; tcount < MAXT; tcount++) tiles[tcount] = -1;   // sentinel
    }
}

// ---- expert fc1: gathered [cnt,KP] x [KP,1024] bf16 GEMM, gelu -> eh bf16 ----
// 1D grid MAXT*8: nt = b&7, ti = b>>3  (blocks 8 apart: same XCD, same nt, next tile)
__global__ __launch_bounds__(256, 4)
void expert_fc1(const u16* __restrict__ xhi, const u16* __restrict__ w1t,
                const float* __restrict__ e_b1, const int* __restrict__ lists,
                const int* __restrict__ counts, const int* __restrict__ tiles,
                u16* __restrict__ eh) {
    int nt = blockIdx.x & 7, ti = blockIdx.x >> 3;
    int info = tiles[ti];
    if (info < 0) return;
    int e = info >> 16, mt = info & 0xFFFF;
    int cnt = counts[e];

    __shared__ u16 lA[128 * BK];
    __shared__ u16 lB[128 * BK];
    __shared__ int rows[128];
    int tt = threadIdx.x;
    if (tt < 128) {
        int m = mt * 128 + tt;
        rows[tt] = lists[(size_t)e * N_TOK + (m < cnt ? m : 0)];   // clamp tail to valid entry
    }
    __syncthreads();

    GEMM_DEFS

    const u16* wb = w1t + (size_t)e * HEXP * KP + (size_t)(nt * 128) * KP;
    const u16* gA[4]; const u16* gB[4];
    #pragma unroll
    for (int i = 0; i < 4; i++) {
        gA[i] = xhi + (size_t)(rows[w * 32 + 8 * i + r8] >> 1) * KP + ce;
        gB[i] = wb + (size_t)(w * 32 + 8 * i + r8) * KP + ce;
    }

    for (int k0 = 0; k0 < KP; k0 += BK) {
        GEMM_KSTEP
    }
    int cn = lane & 15;
    #pragma unroll
    for (int i = 0; i < 4; i++)
        #pragma unroll
        for (int rr = 0; rr < 4; rr++) {
            int ml = wm + i * 16 + q4 * 4 + rr;
            int mg = mt * 128 + ml;
            if (mg < cnt) {
                int entry = rows[ml];
                #pragma unroll
                for (int j = 0; j < 4; j++) {
                    int col = nt * 128 + wn + j * 16 + cn;
                    float v = acc[i][j][rr] + e_b1[(size_t)e * HEXP + col];
                    eh[(size_t)entry * HEXP + col] = f2bf(gelu_exact(v));
                }
            }
        }
}

// ---- expert fc2: gathered [cnt,1024] x [1024,512] bf16 GEMM -> per-slot fp32 outs ----
// 1D grid MAXT*4: nt = b&3, ti = b>>2
__global__ __launch_bounds__(256, 4)
void expert_fc2(const u16* __restrict__ eh, const u16* __restrict__ w2t,
                const int* __restrict__ lists, const int* __restrict__ counts,
                const int* __restrict__ tiles, float* __restrict__ outs) {
    int nt = blockIdx.x & 3, ti = blockIdx.x >> 2;
    int info = tiles[ti];
    if (info < 0) return;
    int e = info >> 16, mt = info & 0xFFFF;
    int cnt = counts[e];

    __shared__ u16 lA[128 * BK];
    __shared__ u16 lB[128 * BK];
    __shared__ int rows[128];
    int tt = threadIdx.x;
    if (tt < 128) {
        int m = mt * 128 + tt;
        rows[tt] = lists[(size_t)e * N_TOK + (m < cnt ? m : 0)];
    }
    __syncthreads();

    GEMM_DEFS

    const u16* wb = w2t + (size_t)e * DMODEL * HEXP + (size_t)(nt * 128) * HEXP;
    const u16* gA[4]; const u16* gB[4];
    #pragma unroll
    for (int i = 0; i < 4; i++) {
        gA[i] = eh + (size_t)rows[w * 32 + 8 * i + r8] * HEXP + ce;
        gB[i] = wb + (size_t)(w * 32 + 8 * i + r8) * HEXP + ce;
    }

    for (int k0 = 0; k0 < HEXP; k0 += BK) {
        GEMM_KSTEP
    }
    int cn = lane & 15;
    #pragma unroll
    for (int i = 0; i < 4; i++)
        #pragma unroll
        for (int rr = 0; rr < 4; rr++) {
            int ml = wm + i * 16 + q4 * 4 + rr;
            int mg = mt * 128 + ml;
            if (mg < cnt) {
                int entry = rows[ml];
                #pragma unroll
                for (int j = 0; j < 4; j++) {
                    int col = nt * 128 + wn + j * 16 + cn;
                    outs[(size_t)entry * DMODEL + col] = acc[i][j][rr];
                }
            }
        }
}

// ---- combine: gate*(outs+b2) + masked residual + final LN ----
__global__ __launch_bounds__(512)
void combine_ln(const float* __restrict__ outs, const float* __restrict__ pgate,
                const int* __restrict__ pexp, const float* __restrict__ e_b2,
                const float* __restrict__ mask, const u16* __restrict__ xhi,
                const u16* __restrict__ xlo, const float* __restrict__ oln_g,
                const float* __restrict__ oln_b, float* __restrict__ out) {
    __shared__ float red[18];
    int n = blockIdx.x, d = threadIdx.x;
    float g0 = pgate[n * 2], g1 = pgate[n * 2 + 1];
    int e0 = pexp[n * 2], e1 = pexp[n * 2 + 1];
    float o = g0 * (outs[(size_t)(n * 2) * DMODEL + d] + e_b2[(size_t)e0 * DMODEL + d])
            + g1 * (outs[(size_t)(n * 2 + 1) * DMODEL + d] + e_b2[(size_t)e1 * DMODEL + d]);
    float m0 = mask[n * 3 + 0], m1 = mask[n * 3 + 1], m2 = mask[n * 3 + 2];
    float denom = fmaxf(m0 + m1 + m2, 1.f);
    size_t xb = (size_t)n * KP;
    float z1n = bf2f(xhi[xb + d]) + bf2f(xlo[xb + d]);                       // hi+lo = fp32-exact
    float z2n = bf2f(xhi[xb + DMODEL + d]) + bf2f(xlo[xb + DMODEL + d]);
    float z3n = bf2f(xhi[xb + 2 * DMODEL + d]) + bf2f(xlo[xb + 2 * DMODEL + d]);
    float z = o + (m0 * z1n + m1 * z2n + m2 * z3n) / denom;
    float2 st = bstats512(z, d, red);
    out[(size_t)n * DMODEL + d] = (z - st.x) * st.y * oln_g[d] + oln_b[d];
}

extern "C" void kernel_launch(void* const* d_in, const int* in_sizes, int n_in,
                              void* d_out, int out_size, void* d_ws, size_t ws_size,
                              hipStream_t stream) {
    (void)in_sizes; (void)n_in; (void)out_size; (void)ws_size;
    const float* z1       = (const float*)d_in[0];
    const float* z2       = (const float*)d_in[1];
    const float* z3       = (const float*)d_in[2];
    const float* mask     = (const float*)d_in[3];
    const float* ln_g     = (const float*)d_in[4];
    const float* ln_b     = (const float*)d_in[5];
    const float* lnp_g    = (const float*)d_in[6];
    const float* lnp_b    = (const float*)d_in[7];
    const float* oln_g    = (const float*)d_in[8];
    const float* oln_b    = (const float*)d_in[9];
    const float* r_w1     = (const float*)d_in[10];
    const float* r_b1     = (const float*)d_in[11];
    const float* r_w2     = (const float*)d_in[12];
    const float* r_b2     = (const float*)d_in[13];
    const float* log_temp = (const float*)d_in[14];
    const float* e_w1     = (const float*)d_in[15];
    const float* e_b1     = (const float*)d_in[16];
    const float* e_w2     = (const float*)d_in[17];
    const float* e_b2     = (const float*)d_in[18];
    float* out = (float*)d_out;

    char* p = (char*)d_ws;
    auto carve = [&](size_t bytes) { char* r = p; p += (bytes + 255) & ~(size_t)255; return r; };
    u16*   xhi    = (u16*)carve((size_t)N_TOK * KP * 2);
    u16*   xlo    = (u16*)carve((size_t)N_TOK * KP * 2);
    u16*   w1t    = (u16*)carve((size_t)NEXP * HEXP * KP * 2);
    u16*   w2t    = (u16*)carve((size_t)NEXP * DMODEL * HEXP * 2);
    u16*   rw1hi  = (u16*)carve((size_t)RHDIM * KP * 2);
    u16*   rw1lo  = (u16*)carve((size_t)RHDIM * KP * 2);
    float* rpart  = (float*)carve((size_t)6 * N_TOK * RHDIM * 4);
    u16*   eh     = (u16*)carve((size_t)NPAIR * HEXP * 2);
    float* outsb  = (float*)carve((size_t)NPAIR * DMODEL * 4);
    float* pgate  = (float*)carve((size_t)NPAIR * 4);
    int*   pexp   = (int*)carve((size_t)NPAIR * 4);
    int*   lists  = (int*)carve((size_t)NEXP * N_TOK * 4);
    int*   counts = (int*)carve(256);
    int*   tiles  = (int*)carve(MAXT * 4);

    dim3 tb(32, 8);
    transpose_f32_bf16<<<dim3(KP / 32, HEXP / 32, NEXP), tb, 0, stream>>>(
        e_w1, w1t, (u16*)nullptr, IN_REAL, KP, HEXP, (size_t)IN_REAL * HEXP, (size_t)HEXP * KP);
    transpose_f32_bf16<<<dim3(HEXP / 32, DMODEL / 32, NEXP), tb, 0, stream>>>(
        e_w2, w2t, (u16*)nullptr, HEXP, HEXP, DMODEL, (size_t)HEXP * DMODEL, (size_t)DMODEL * HEXP);
    transpose_f32_bf16<<<dim3(KP / 32, RHDIM / 32, 1), tb, 0, stream>>>(
        r_w1, rw1hi, rw1lo, IN_REAL, KP, RHDIM, (size_t)0, (size_t)0);

    build_x<<<N_TOK, 512, 0, stream>>>(z1, z2, z3, mask, ln_g, ln_b, lnp_g, lnp_b, xhi, xlo);

    router_fc1<<<768, 256, 0, stream>>>(xhi, xlo, rw1hi, rw1lo, rpart);

    hipMemsetAsync(counts, 0, 256, stream);
    logits_topk<<<N_TOK / 4, 256, 0, stream>>>(rpart, r_b1, r_w2, r_b2, log_temp,
                                               pgate, pexp, lists, counts);
    sched_tiles<<<1, 64, 0, stream>>>(counts, tiles);

    expert_fc1<<<MAXT * 8, 256, 0, stream>>>(xhi, w1t, e_b1, lists, counts, tiles, eh);
    expert_fc2<<<MAXT * 4, 256, 0, stream>>>(eh, w2t, lists, counts, tiles, outsb);

    combine_ln<<<N_TOK, 512, 0, stream>>>(outsb, pgate, pexp, e_b2, mask, xhi, xlo, oln_g, oln_b, out);
}